// Round 2
// baseline (5739.594 us; speedup 1.0000x reference)
//
#include <hip/hip_runtime.h>

// ChebConv(K=3) + PReLU + BatchNorm, N=100000 nodes, E=1.6e6 edges, 128->128.
// Pipeline:
//   deg -> dinv -> ew  (edge weights of scaled Laplacian, zero diag)
//   tx1 = prop(x)          [scatter-add over edges]
//   tx2 = 2*prop(tx1) - x  [init tx2=-x, scatter with scale=2]
//   out = x@W0 + tx1@W1 + tx2@W2 + bias ; PReLU
//   batchnorm over nodes (biased var), gamma/beta

#define DIM 128

__global__ __launch_bounds__(256) void deg_kernel(const int* __restrict__ row,
                                                  float* __restrict__ deg, int E) {
    int e = blockIdx.x * 256 + threadIdx.x;
    if (e < E) atomicAdd(&deg[row[e]], 1.0f);
}

__global__ __launch_bounds__(256) void dinv_kernel(const float* __restrict__ deg,
                                                   float* __restrict__ dinv, int n) {
    int i = blockIdx.x * 256 + threadIdx.x;
    if (i < n) {
        float d = deg[i];
        dinv[i] = d > 0.f ? rsqrtf(d) : 0.f;
    }
}

__global__ __launch_bounds__(256) void ew_kernel(const int* __restrict__ row,
                                                 const int* __restrict__ col,
                                                 const float* __restrict__ dinv,
                                                 float* __restrict__ ew, int E) {
    int e = blockIdx.x * 256 + threadIdx.x;
    if (e < E) ew[e] = -dinv[row[e]] * dinv[col[e]];
}

__global__ __launch_bounds__(256) void neg_copy_kernel(const float* __restrict__ x,
                                                       float* __restrict__ out, int n4) {
    int i = blockIdx.x * 256 + threadIdx.x;
    if (i < n4) {
        float4 v = ((const float4*)x)[i];
        ((float4*)out)[i] = make_float4(-v.x, -v.y, -v.z, -v.w);
    }
}

// One edge handled by 32 threads (4 floats each). scatter: xout[row] += scale*ew*xin[col]
__global__ __launch_bounds__(256) void prop_kernel(const float* __restrict__ xin,
                                                   float* __restrict__ xout,
                                                   const float* __restrict__ ew,
                                                   const int* __restrict__ row,
                                                   const int* __restrict__ col,
                                                   float scale, int E) {
    int idx = blockIdx.x * 256 + threadIdx.x;
    if (idx >= E * 32) return;
    int e = idx >> 5, c = idx & 31;
    float w = ew[e] * scale;
    if (w == 0.f) return;
    int ci = col[e], ri = row[e];
    float4 v = ((const float4*)xin)[ci * 32 + c];
    float* dst = xout + (size_t)ri * DIM + c * 4;
    atomicAdd(dst + 0, w * v.x);
    atomicAdd(dst + 1, w * v.y);
    atomicAdd(dst + 2, w * v.z);
    atomicAdd(dst + 3, w * v.w);
}

__device__ __forceinline__ void fma4(float4& a, float s, const float4& b) {
    a.x = fmaf(s, b.x, a.x);
    a.y = fmaf(s, b.y, a.y);
    a.z = fmaf(s, b.z, a.z);
    a.w = fmaf(s, b.w, a.w);
}

// 256 threads: 32 rows x 128 cols per block. W and x chunks staged in LDS.
// thread: jg = tid&31 -> cols j4..j4+3 ; rg = tid>>5 -> rows rg*4..rg*4+3
__global__ __launch_bounds__(256) void gemm_kernel(const float* __restrict__ tx0,
                                                   const float* __restrict__ tx1,
                                                   const float* __restrict__ tx2,
                                                   const float* __restrict__ W,
                                                   const float* __restrict__ bias,
                                                   const float* __restrict__ prelu_a,
                                                   float* __restrict__ out) {
    __shared__ __align__(16) float lw[3 * 32 * 128];  // [m][kk][j]
    __shared__ __align__(16) float lx[32 * 96];       // [r][m*32+kk]
    const int tid = threadIdx.x;
    const int jg = tid & 31, j4 = jg * 4;
    const int rg = tid >> 5;
    const size_t r0 = (size_t)blockIdx.x * 32;

    float4 acc[4];
    {
        float4 b = *(const float4*)&bias[j4];
        acc[0] = b; acc[1] = b; acc[2] = b; acc[3] = b;
    }

    for (int kc = 0; kc < 4; ++kc) {
        if (kc) __syncthreads();
        // stage W chunk: 3 matrices x 32 k x 128 j = 12288 floats
        #pragma unroll
        for (int t = tid; t < 3072; t += 256) {
            int f = t * 4;
            int m = f >> 12;
            int rem = f & 4095;
            int kk = rem >> 7;
            int j = rem & 127;
            *(float4*)&lw[f] = *(const float4*)&W[m * 16384 + (kc * 32 + kk) * 128 + j];
        }
        // stage x chunk: 32 rows x (3 mats x 32 k) = 3072 floats
        #pragma unroll
        for (int t = tid; t < 768; t += 256) {
            int f = t * 4;
            int r = f / 96;
            int c = f - r * 96;
            int m = c >> 5;
            int kk = c & 31;
            const float* src = (m == 0) ? tx0 : ((m == 1) ? tx1 : tx2);
            *(float4*)&lx[f] = *(const float4*)&src[(r0 + r) * DIM + kc * 32 + kk];
        }
        __syncthreads();

        #pragma unroll
        for (int k4 = 0; k4 < 8; ++k4) {
            #pragma unroll
            for (int m = 0; m < 3; ++m) {
                float4 wv0 = *(float4*)&lw[(m * 32 + k4 * 4 + 0) * 128 + j4];
                float4 wv1 = *(float4*)&lw[(m * 32 + k4 * 4 + 1) * 128 + j4];
                float4 wv2 = *(float4*)&lw[(m * 32 + k4 * 4 + 2) * 128 + j4];
                float4 wv3 = *(float4*)&lw[(m * 32 + k4 * 4 + 3) * 128 + j4];
                #pragma unroll
                for (int rr = 0; rr < 4; ++rr) {
                    float4 xv = *(float4*)&lx[(rg * 4 + rr) * 96 + m * 32 + k4 * 4];
                    fma4(acc[rr], xv.x, wv0);
                    fma4(acc[rr], xv.y, wv1);
                    fma4(acc[rr], xv.z, wv2);
                    fma4(acc[rr], xv.w, wv3);
                }
            }
        }
    }

    const float a = prelu_a[0];
    #pragma unroll
    for (int rr = 0; rr < 4; ++rr) {
        float4 v = acc[rr];
        v.x = v.x > 0.f ? v.x : a * v.x;
        v.y = v.y > 0.f ? v.y : a * v.y;
        v.z = v.z > 0.f ? v.z : a * v.z;
        v.w = v.w > 0.f ? v.w : a * v.w;
        *(float4*)&out[(r0 + rg * 4 + rr) * DIM + j4] = v;
    }
}

// per-channel sum and sum-of-squares over all N rows
__global__ __launch_bounds__(256) void stats_kernel(const float* __restrict__ out,
                                                    float* __restrict__ stats, int total4) {
    __shared__ __align__(16) float ss[1024], sq[1024];
    int tid = threadIdx.x;
    float4 s = make_float4(0.f, 0.f, 0.f, 0.f);
    float4 q = make_float4(0.f, 0.f, 0.f, 0.f);
    for (int i = blockIdx.x * 256 + tid; i < total4; i += gridDim.x * 256) {
        float4 v = ((const float4*)out)[i];
        s.x += v.x; s.y += v.y; s.z += v.z; s.w += v.w;
        q.x += v.x * v.x; q.y += v.y * v.y; q.z += v.z * v.z; q.w += v.w * v.w;
    }
    int c4 = tid & 31, g = tid >> 5;
    *(float4*)&ss[g * 128 + c4 * 4] = s;
    *(float4*)&sq[g * 128 + c4 * 4] = q;
    __syncthreads();
    if (tid < 128) {
        float as = 0.f, aq = 0.f;
        #pragma unroll
        for (int g2 = 0; g2 < 8; ++g2) {
            as += ss[g2 * 128 + tid];
            aq += sq[g2 * 128 + tid];
        }
        atomicAdd(&stats[tid], as);
        atomicAdd(&stats[128 + tid], aq);
    }
}

__global__ void bn_prep_kernel(float* __restrict__ stats, const float* __restrict__ gamma,
                               const float* __restrict__ beta, float invN) {
    int c = threadIdx.x;  // 128 threads
    float mean = stats[c] * invN;
    float var = stats[128 + c] * invN - mean * mean;
    float sc = gamma[c] * rsqrtf(var + 1e-5f);
    stats[256 + c] = sc;
    stats[384 + c] = beta[c] - mean * sc;
}

__global__ __launch_bounds__(256) void bn_apply_kernel(float* __restrict__ out,
                                                       const float* __restrict__ scale,
                                                       const float* __restrict__ shift,
                                                       int total4) {
    int i0 = blockIdx.x * 256 + threadIdx.x;
    int stride = gridDim.x * 256;  // multiple of 32 -> channel group fixed per thread
    int c4 = i0 & 31;
    float4 sc = *(const float4*)&scale[c4 * 4];
    float4 sh = *(const float4*)&shift[c4 * 4];
    for (int i = i0; i < total4; i += stride) {
        float4 v = ((float4*)out)[i];
        v.x = v.x * sc.x + sh.x;
        v.y = v.y * sc.y + sh.y;
        v.z = v.z * sc.z + sh.z;
        v.w = v.w * sc.w + sh.w;
        ((float4*)out)[i] = v;
    }
}

extern "C" void kernel_launch(void* const* d_in, const int* in_sizes, int n_in,
                              void* d_out, int out_size, void* d_ws, size_t ws_size,
                              hipStream_t stream) {
    const float* x = (const float*)d_in[0];
    const int* ei = (const int*)d_in[1];
    const float* W = (const float*)d_in[2];
    const float* bias = (const float*)d_in[3];
    const float* prelu_a = (const float*)d_in[4];
    const float* gamma = (const float*)d_in[5];
    const float* beta = (const float*)d_in[6];
    float* out = (float*)d_out;

    const int N = in_sizes[0] / DIM;  // 100000
    const int E = in_sizes[1] / 2;    // 1600000
    const int* row = ei;
    const int* col = ei + E;

    // workspace layout (1KB-aligned regions)
    char* ws = (char*)d_ws;
    size_t off = 0;
    auto take = [&](size_t bytes) {
        size_t p = off;
        off = (off + bytes + 1023) & ~(size_t)1023;
        return p;
    };
    float* deg   = (float*)(ws + take((size_t)N * 4));
    float* dinv  = (float*)(ws + take((size_t)N * 4));
    float* ew    = (float*)(ws + take((size_t)E * 4));
    float* stats = (float*)(ws + take(512 * 4));          // sum | sumsq | scale | shift
    float* tx1   = (float*)(ws + take((size_t)N * DIM * 4));
    float* tx2   = (float*)(ws + take((size_t)N * DIM * 4));

    (void)hipMemsetAsync(deg, 0, (size_t)N * 4, stream);
    (void)hipMemsetAsync(stats, 0, 512 * 4, stream);
    (void)hipMemsetAsync(tx1, 0, (size_t)N * DIM * 4, stream);

    deg_kernel<<<(E + 255) / 256, 256, 0, stream>>>(row, deg, E);
    dinv_kernel<<<(N + 255) / 256, 256, 0, stream>>>(deg, dinv, N);
    ew_kernel<<<(E + 255) / 256, 256, 0, stream>>>(row, col, dinv, ew, E);

    int propBlocks = (E * 32 + 255) / 256;
    prop_kernel<<<propBlocks, 256, 0, stream>>>(x, tx1, ew, row, col, 1.0f, E);
    neg_copy_kernel<<<(N * 32 + 255) / 256, 256, 0, stream>>>(x, tx2, N * 32);
    prop_kernel<<<propBlocks, 256, 0, stream>>>(tx1, tx2, ew, row, col, 2.0f, E);

    gemm_kernel<<<N / 32, 256, 0, stream>>>(x, tx1, tx2, W, bias, prelu_a, out);

    stats_kernel<<<1024, 256, 0, stream>>>(out, stats, N * 32);
    bn_prep_kernel<<<1, 128, 0, stream>>>(stats, gamma, beta, 1.0f / (float)N);
    bn_apply_kernel<<<2048, 256, 0, stream>>>(out, stats + 256, stats + 384, N * 32);
}

// Round 3
// 749.600 us; speedup vs baseline: 7.6569x; 7.6569x over previous
//
#include <hip/hip_runtime.h>

// ChebConv(K=3) + PReLU + BatchNorm, N=100000, E=1.6e6, 128->128.
// R3: scatter-atomic prop replaced by CSR build + gather prop (no float atomics).

#define DIM 128

// ---------------- degree / dinv ----------------
__global__ __launch_bounds__(256) void deg_kernel(const int* __restrict__ row,
                                                  int* __restrict__ deg, int E) {
    int e = blockIdx.x * 256 + threadIdx.x;
    if (e < E) atomicAdd(&deg[row[e]], 1);
}

__global__ __launch_bounds__(256) void dinv_kernel(const int* __restrict__ deg,
                                                   float* __restrict__ dinv, int n) {
    int i = blockIdx.x * 256 + threadIdx.x;
    if (i < n) {
        int d = deg[i];
        dinv[i] = d > 0 ? rsqrtf((float)d) : 0.f;
    }
}

// ---------------- prefix scan (3 kernels) ----------------
#define SCAN_T 256
#define SCAN_I 4
#define SCAN_ELEMS (SCAN_T * SCAN_I)

__global__ __launch_bounds__(SCAN_T) void scan1_kernel(const int* __restrict__ deg,
                                                       int* __restrict__ partial,
                                                       int* __restrict__ blockSums, int n) {
    __shared__ int lds[SCAN_T];
    int tbase = blockIdx.x * SCAN_ELEMS + threadIdx.x * SCAN_I;
    int v[SCAN_I];
    int tsum = 0;
    #pragma unroll
    for (int k = 0; k < SCAN_I; ++k) {
        int i = tbase + k;
        v[k] = (i < n) ? deg[i] : 0;
        tsum += v[k];
    }
    lds[threadIdx.x] = tsum;
    __syncthreads();
    int val = tsum;
    for (int off = 1; off < SCAN_T; off <<= 1) {
        int y = (threadIdx.x >= off) ? lds[threadIdx.x - off] : 0;
        __syncthreads();
        val += y;
        lds[threadIdx.x] = val;
        __syncthreads();
    }
    if (threadIdx.x == SCAN_T - 1) blockSums[blockIdx.x] = val;
    int run = val - tsum;  // exclusive prefix for this thread
    #pragma unroll
    for (int k = 0; k < SCAN_I; ++k) {
        int i = tbase + k;
        if (i < n) partial[i] = run;
        run += v[k];
    }
}

__global__ __launch_bounds__(256) void scan2_kernel(int* __restrict__ blockSums, int nb) {
    __shared__ int lds[256];
    int v = (threadIdx.x < nb) ? blockSums[threadIdx.x] : 0;
    lds[threadIdx.x] = v;
    __syncthreads();
    int val = v;
    for (int off = 1; off < 256; off <<= 1) {
        int y = (threadIdx.x >= off) ? lds[threadIdx.x - off] : 0;
        __syncthreads();
        val += y;
        lds[threadIdx.x] = val;
        __syncthreads();
    }
    if (threadIdx.x < nb) blockSums[threadIdx.x] = val - v;  // exclusive
}

__global__ __launch_bounds__(256) void scan3_kernel(int* __restrict__ row_ptr,
                                                    const int* __restrict__ blockSums,
                                                    int* __restrict__ cursor, int n, int E) {
    int i = blockIdx.x * 256 + threadIdx.x;
    if (i < n) {
        int v = row_ptr[i] + blockSums[i / SCAN_ELEMS];
        row_ptr[i] = v;
        cursor[i] = v;
    }
    if (i == 0) row_ptr[n] = E;
}

__global__ __launch_bounds__(256) void fill_kernel(const int* __restrict__ row,
                                                   const int* __restrict__ col,
                                                   int* __restrict__ cursor,
                                                   int* __restrict__ colS, int E) {
    int e = blockIdx.x * 256 + threadIdx.x;
    if (e < E) {
        int pos = atomicAdd(&cursor[row[e]], 1);
        colS[pos] = col[e];
    }
}

// ---------------- gather propagation ----------------
// One row per 64-lane wave; lane owns float2 at column lane*2.
// out[i] = -alpha * dinv[i] * sum_e dinv[colS[e]] * xin[colS[e]]  (+ addscale*addsrc[i])
__global__ __launch_bounds__(256) void gather_kernel(const float* __restrict__ xin,
                                                     const float* __restrict__ addsrc,
                                                     float addscale, float alpha,
                                                     const int* __restrict__ row_ptr,
                                                     const int* __restrict__ colS,
                                                     const float* __restrict__ dinv,
                                                     float* __restrict__ xout, int n) {
    int wid = (blockIdx.x * 256 + threadIdx.x) >> 6;
    int lane = threadIdx.x & 63;
    if (wid >= n) return;
    int e = row_ptr[wid];
    int end = row_ptr[wid + 1];
    float2 acc0 = make_float2(0.f, 0.f), acc1 = make_float2(0.f, 0.f);
    for (; e + 1 < end; e += 2) {
        int c0 = colS[e], c1 = colS[e + 1];
        float w0 = dinv[c0], w1 = dinv[c1];
        float2 v0 = *(const float2*)&xin[(size_t)c0 * DIM + lane * 2];
        float2 v1 = *(const float2*)&xin[(size_t)c1 * DIM + lane * 2];
        acc0.x = fmaf(w0, v0.x, acc0.x);
        acc0.y = fmaf(w0, v0.y, acc0.y);
        acc1.x = fmaf(w1, v1.x, acc1.x);
        acc1.y = fmaf(w1, v1.y, acc1.y);
    }
    if (e < end) {
        int c0 = colS[e];
        float w0 = dinv[c0];
        float2 v0 = *(const float2*)&xin[(size_t)c0 * DIM + lane * 2];
        acc0.x = fmaf(w0, v0.x, acc0.x);
        acc0.y = fmaf(w0, v0.y, acc0.y);
    }
    float s = -alpha * dinv[wid];
    float2 o;
    o.x = s * (acc0.x + acc1.x);
    o.y = s * (acc0.y + acc1.y);
    if (addsrc) {
        float2 a = *(const float2*)&addsrc[(size_t)wid * DIM + lane * 2];
        o.x = fmaf(addscale, a.x, o.x);
        o.y = fmaf(addscale, a.y, o.y);
    }
    *(float2*)&xout[(size_t)wid * DIM + lane * 2] = o;
}

// ---------------- GEMM + PReLU ----------------
__device__ __forceinline__ void fma4(float4& a, float s, const float4& b) {
    a.x = fmaf(s, b.x, a.x);
    a.y = fmaf(s, b.y, a.y);
    a.z = fmaf(s, b.z, a.z);
    a.w = fmaf(s, b.w, a.w);
}

// 256 threads: 32 rows x 128 cols per block. W and x chunks staged in LDS.
__global__ __launch_bounds__(256) void gemm_kernel(const float* __restrict__ tx0,
                                                   const float* __restrict__ tx1,
                                                   const float* __restrict__ tx2,
                                                   const float* __restrict__ W,
                                                   const float* __restrict__ bias,
                                                   const float* __restrict__ prelu_a,
                                                   float* __restrict__ out) {
    __shared__ __align__(16) float lw[3 * 32 * 128];  // [m][kk][j]
    __shared__ __align__(16) float lx[32 * 96];       // [r][m*32+kk]
    const int tid = threadIdx.x;
    const int jg = tid & 31, j4 = jg * 4;
    const int rg = tid >> 5;
    const size_t r0 = (size_t)blockIdx.x * 32;

    float4 acc[4];
    {
        float4 b = *(const float4*)&bias[j4];
        acc[0] = b; acc[1] = b; acc[2] = b; acc[3] = b;
    }

    for (int kc = 0; kc < 4; ++kc) {
        if (kc) __syncthreads();
        #pragma unroll
        for (int t = tid; t < 3072; t += 256) {
            int f = t * 4;
            int m = f >> 12;
            int rem = f & 4095;
            int kk = rem >> 7;
            int j = rem & 127;
            *(float4*)&lw[f] = *(const float4*)&W[m * 16384 + (kc * 32 + kk) * 128 + j];
        }
        #pragma unroll
        for (int t = tid; t < 768; t += 256) {
            int f = t * 4;
            int r = f / 96;
            int c = f - r * 96;
            int m = c >> 5;
            int kk = c & 31;
            const float* src = (m == 0) ? tx0 : ((m == 1) ? tx1 : tx2);
            *(float4*)&lx[f] = *(const float4*)&src[(r0 + r) * DIM + kc * 32 + kk];
        }
        __syncthreads();

        #pragma unroll
        for (int k4 = 0; k4 < 8; ++k4) {
            #pragma unroll
            for (int m = 0; m < 3; ++m) {
                float4 wv0 = *(float4*)&lw[(m * 32 + k4 * 4 + 0) * 128 + j4];
                float4 wv1 = *(float4*)&lw[(m * 32 + k4 * 4 + 1) * 128 + j4];
                float4 wv2 = *(float4*)&lw[(m * 32 + k4 * 4 + 2) * 128 + j4];
                float4 wv3 = *(float4*)&lw[(m * 32 + k4 * 4 + 3) * 128 + j4];
                #pragma unroll
                for (int rr = 0; rr < 4; ++rr) {
                    float4 xv = *(float4*)&lx[(rg * 4 + rr) * 96 + m * 32 + k4 * 4];
                    fma4(acc[rr], xv.x, wv0);
                    fma4(acc[rr], xv.y, wv1);
                    fma4(acc[rr], xv.z, wv2);
                    fma4(acc[rr], xv.w, wv3);
                }
            }
        }
    }

    const float a = prelu_a[0];
    #pragma unroll
    for (int rr = 0; rr < 4; ++rr) {
        float4 v = acc[rr];
        v.x = v.x > 0.f ? v.x : a * v.x;
        v.y = v.y > 0.f ? v.y : a * v.y;
        v.z = v.z > 0.f ? v.z : a * v.z;
        v.w = v.w > 0.f ? v.w : a * v.w;
        *(float4*)&out[(r0 + rg * 4 + rr) * DIM + j4] = v;
    }
}

// ---------------- batchnorm ----------------
__global__ __launch_bounds__(256) void stats_kernel(const float* __restrict__ out,
                                                    float* __restrict__ stats, int total4) {
    __shared__ __align__(16) float ss[1024], sq[1024];
    int tid = threadIdx.x;
    float4 s = make_float4(0.f, 0.f, 0.f, 0.f);
    float4 q = make_float4(0.f, 0.f, 0.f, 0.f);
    for (int i = blockIdx.x * 256 + tid; i < total4; i += gridDim.x * 256) {
        float4 v = ((const float4*)out)[i];
        s.x += v.x; s.y += v.y; s.z += v.z; s.w += v.w;
        q.x += v.x * v.x; q.y += v.y * v.y; q.z += v.z * v.z; q.w += v.w * v.w;
    }
    int c4 = tid & 31, g = tid >> 5;
    *(float4*)&ss[g * 128 + c4 * 4] = s;
    *(float4*)&sq[g * 128 + c4 * 4] = q;
    __syncthreads();
    if (tid < 128) {
        float as = 0.f, aq = 0.f;
        #pragma unroll
        for (int g2 = 0; g2 < 8; ++g2) {
            as += ss[g2 * 128 + tid];
            aq += sq[g2 * 128 + tid];
        }
        atomicAdd(&stats[tid], as);
        atomicAdd(&stats[128 + tid], aq);
    }
}

__global__ void bn_prep_kernel(float* __restrict__ stats, const float* __restrict__ gamma,
                               const float* __restrict__ beta, float invN) {
    int c = threadIdx.x;  // 128 threads
    float mean = stats[c] * invN;
    float var = stats[128 + c] * invN - mean * mean;
    float sc = gamma[c] * rsqrtf(var + 1e-5f);
    stats[256 + c] = sc;
    stats[384 + c] = beta[c] - mean * sc;
}

__global__ __launch_bounds__(256) void bn_apply_kernel(float* __restrict__ out,
                                                       const float* __restrict__ scale,
                                                       const float* __restrict__ shift,
                                                       int total4) {
    int i0 = blockIdx.x * 256 + threadIdx.x;
    int stride = gridDim.x * 256;
    int c4 = i0 & 31;
    float4 sc = *(const float4*)&scale[c4 * 4];
    float4 sh = *(const float4*)&shift[c4 * 4];
    for (int i = i0; i < total4; i += stride) {
        float4 v = ((float4*)out)[i];
        v.x = v.x * sc.x + sh.x;
        v.y = v.y * sc.y + sh.y;
        v.z = v.z * sc.z + sh.z;
        v.w = v.w * sc.w + sh.w;
        ((float4*)out)[i] = v;
    }
}

extern "C" void kernel_launch(void* const* d_in, const int* in_sizes, int n_in,
                              void* d_out, int out_size, void* d_ws, size_t ws_size,
                              hipStream_t stream) {
    const float* x = (const float*)d_in[0];
    const int* ei = (const int*)d_in[1];
    const float* W = (const float*)d_in[2];
    const float* bias = (const float*)d_in[3];
    const float* prelu_a = (const float*)d_in[4];
    const float* gamma = (const float*)d_in[5];
    const float* beta = (const float*)d_in[6];
    float* out = (float*)d_out;

    const int N = in_sizes[0] / DIM;  // 100000
    const int E = in_sizes[1] / 2;    // 1600000
    const int* row = ei;
    const int* col = ei + E;

    char* ws = (char*)d_ws;
    size_t off = 0;
    auto take = [&](size_t bytes) {
        size_t p = off;
        off = (off + bytes + 1023) & ~(size_t)1023;
        return p;
    };
    int* deg        = (int*)(ws + take((size_t)N * 4));        // later reused as cursor
    float* dinv     = (float*)(ws + take((size_t)N * 4));
    int* row_ptr    = (int*)(ws + take((size_t)(N + 1) * 4));
    int* blockSums  = (int*)(ws + take(256 * 4));
    float* stats    = (float*)(ws + take(512 * 4));
    int* colS       = (int*)(ws + take((size_t)E * 4));
    float* tx1      = (float*)(ws + take((size_t)N * DIM * 4));
    float* tx2      = (float*)(ws + take((size_t)N * DIM * 4));

    (void)hipMemsetAsync(deg, 0, (size_t)N * 4, stream);
    (void)hipMemsetAsync(stats, 0, 512 * 4, stream);

    deg_kernel<<<(E + 255) / 256, 256, 0, stream>>>(row, deg, E);
    dinv_kernel<<<(N + 255) / 256, 256, 0, stream>>>(deg, dinv, N);

    int nb = (N + SCAN_ELEMS - 1) / SCAN_ELEMS;  // 98
    scan1_kernel<<<nb, SCAN_T, 0, stream>>>(deg, row_ptr, blockSums, N);
    scan2_kernel<<<1, 256, 0, stream>>>(blockSums, nb);
    scan3_kernel<<<(N + 255) / 256, 256, 0, stream>>>(row_ptr, blockSums, deg /*cursor*/, N, E);
    fill_kernel<<<(E + 255) / 256, 256, 0, stream>>>(row, col, deg /*cursor*/, colS, E);

    int gatherBlocks = (N * 64 + 255) / 256;
    gather_kernel<<<gatherBlocks, 256, 0, stream>>>(x, nullptr, 0.f, 1.0f,
                                                    row_ptr, colS, dinv, tx1, N);
    gather_kernel<<<gatherBlocks, 256, 0, stream>>>(tx1, x, -1.0f, 2.0f,
                                                    row_ptr, colS, dinv, tx2, N);

    gemm_kernel<<<N / 32, 256, 0, stream>>>(x, tx1, tx2, W, bias, prelu_a, out);

    stats_kernel<<<1024, 256, 0, stream>>>(out, stats, N * 32);
    bn_prep_kernel<<<1, 128, 0, stream>>>(stats, gamma, beta, 1.0f / (float)N);
    bn_apply_kernel<<<2048, 256, 0, stream>>>(out, stats + 256, stats + 384, N * 32);
}

// Round 5
// 486.375 us; speedup vs baseline: 11.8008x; 1.5412x over previous
//
#include <hip/hip_runtime.h>

// ChebConv(K=3) + PReLU + BatchNorm, N=100000, E=1.6e6, 128->128.
// R5: R4 with the wlds staging index fixed (48 16B-chunks per 384-short row).

#define DIM 128
#define K3 384

typedef __attribute__((ext_vector_type(8))) short short8;
typedef __attribute__((ext_vector_type(4))) float f32x4;

__device__ __forceinline__ short f2bf(float f) {
    union { float f; unsigned u; } v{f};
    unsigned r = (v.u + 0x7FFF + ((v.u >> 16) & 1)) >> 16;  // RNE
    return (short)r;
}
__device__ __forceinline__ float bflo(unsigned p) {
    union { unsigned u; float f; } v{p << 16};
    return v.f;
}
__device__ __forceinline__ float bfhi(unsigned p) {
    union { unsigned u; float f; } v{p & 0xFFFF0000u};
    return v.f;
}

// ---------------- degree / dinv ----------------
__global__ __launch_bounds__(256) void deg_kernel(const int* __restrict__ row,
                                                  int* __restrict__ deg, int E) {
    int e = blockIdx.x * 256 + threadIdx.x;
    if (e < E) atomicAdd(&deg[row[e]], 1);
}

__global__ __launch_bounds__(256) void dinv_kernel(const int* __restrict__ deg,
                                                   float* __restrict__ dinv, int n) {
    int i = blockIdx.x * 256 + threadIdx.x;
    if (i < n) {
        int d = deg[i];
        dinv[i] = d > 0 ? rsqrtf((float)d) : 0.f;
    }
}

// ---------------- prefix scan ----------------
#define SCAN_T 256
#define SCAN_I 4
#define SCAN_ELEMS (SCAN_T * SCAN_I)

__global__ __launch_bounds__(SCAN_T) void scan1_kernel(const int* __restrict__ deg,
                                                       int* __restrict__ partial,
                                                       int* __restrict__ blockSums, int n) {
    __shared__ int lds[SCAN_T];
    int tbase = blockIdx.x * SCAN_ELEMS + threadIdx.x * SCAN_I;
    int v[SCAN_I];
    int tsum = 0;
    #pragma unroll
    for (int k = 0; k < SCAN_I; ++k) {
        int i = tbase + k;
        v[k] = (i < n) ? deg[i] : 0;
        tsum += v[k];
    }
    lds[threadIdx.x] = tsum;
    __syncthreads();
    int val = tsum;
    for (int off = 1; off < SCAN_T; off <<= 1) {
        int y = (threadIdx.x >= off) ? lds[threadIdx.x - off] : 0;
        __syncthreads();
        val += y;
        lds[threadIdx.x] = val;
        __syncthreads();
    }
    if (threadIdx.x == SCAN_T - 1) blockSums[blockIdx.x] = val;
    int run = val - tsum;
    #pragma unroll
    for (int k = 0; k < SCAN_I; ++k) {
        int i = tbase + k;
        if (i < n) partial[i] = run;
        run += v[k];
    }
}

__global__ __launch_bounds__(256) void scan2_kernel(int* __restrict__ blockSums, int nb) {
    __shared__ int lds[256];
    int v = (threadIdx.x < nb) ? blockSums[threadIdx.x] : 0;
    lds[threadIdx.x] = v;
    __syncthreads();
    int val = v;
    for (int off = 1; off < 256; off <<= 1) {
        int y = (threadIdx.x >= off) ? lds[threadIdx.x - off] : 0;
        __syncthreads();
        val += y;
        lds[threadIdx.x] = val;
        __syncthreads();
    }
    if (threadIdx.x < nb) blockSums[threadIdx.x] = val - v;
}

__global__ __launch_bounds__(256) void scan3_kernel(int* __restrict__ row_ptr,
                                                    const int* __restrict__ blockSums,
                                                    int* __restrict__ cursor, int n, int E) {
    int i = blockIdx.x * 256 + threadIdx.x;
    if (i < n) {
        int v = row_ptr[i] + blockSums[i / SCAN_ELEMS];
        row_ptr[i] = v;
        cursor[i] = v;
    }
    if (i == 0) row_ptr[n] = E;
}

__global__ __launch_bounds__(256) void fill_kernel(const int* __restrict__ row,
                                                   const int* __restrict__ col,
                                                   int* __restrict__ cursor,
                                                   int* __restrict__ colS, int E) {
    int e = blockIdx.x * 256 + threadIdx.x;
    if (e < E) {
        int pos = atomicAdd(&cursor[row[e]], 1);
        colS[pos] = col[e];
    }
}

// ---------------- converts ----------------
__global__ __launch_bounds__(384) void wbt_prep_kernel(const float* __restrict__ W,
                                                       short* __restrict__ WbT) {
    int j = blockIdx.x;       // 0..127
    int kk = threadIdx.x;     // 0..383
    WbT[j * K3 + kk] = f2bf(W[kk * DIM + j]);
}

__global__ __launch_bounds__(256) void convert_x_kernel(const float* __restrict__ x,
                                                        short* __restrict__ Xcat, int n32) {
    int tid = blockIdx.x * 256 + threadIdx.x;
    if (tid >= n32) return;
    int i = tid >> 5, seg = tid & 31;
    float4 v = *(const float4*)&x[(size_t)i * DIM + seg * 4];
    short4 o;
    o.x = f2bf(v.x); o.y = f2bf(v.y); o.z = f2bf(v.z); o.w = f2bf(v.w);
    *(short4*)&Xcat[(size_t)i * K3 + seg * 4] = o;
}

// ---------------- gather propagation (bf16 in, bf16 out) ----------------
__global__ __launch_bounds__(256) void gather1_kernel(short* __restrict__ Xcat,
                                                      const int* __restrict__ row_ptr,
                                                      const int* __restrict__ colS,
                                                      const float* __restrict__ dinv, int n) {
    int wid = (blockIdx.x * 256 + threadIdx.x) >> 6;
    int lane = threadIdx.x & 63;
    if (wid >= n) return;
    int e = row_ptr[wid], end = row_ptr[wid + 1];
    float a0 = 0.f, a1 = 0.f, b0 = 0.f, b1 = 0.f;
    for (; e + 1 < end; e += 2) {
        int c0 = colS[e], c1 = colS[e + 1];
        float w0 = dinv[c0], w1 = dinv[c1];
        unsigned p0 = *(const unsigned*)&Xcat[(size_t)c0 * K3 + lane * 2];
        unsigned p1 = *(const unsigned*)&Xcat[(size_t)c1 * K3 + lane * 2];
        a0 = fmaf(w0, bflo(p0), a0);
        a1 = fmaf(w0, bfhi(p0), a1);
        b0 = fmaf(w1, bflo(p1), b0);
        b1 = fmaf(w1, bfhi(p1), b1);
    }
    if (e < end) {
        int c0 = colS[e];
        float w0 = dinv[c0];
        unsigned p0 = *(const unsigned*)&Xcat[(size_t)c0 * K3 + lane * 2];
        a0 = fmaf(w0, bflo(p0), a0);
        a1 = fmaf(w0, bfhi(p0), a1);
    }
    float s = -dinv[wid];
    float o0 = s * (a0 + b0), o1 = s * (a1 + b1);
    unsigned pk = ((unsigned)(unsigned short)f2bf(o1) << 16) | (unsigned short)f2bf(o0);
    *(unsigned*)&Xcat[(size_t)wid * K3 + 128 + lane * 2] = pk;
}

__global__ __launch_bounds__(256) void gather2_kernel(short* __restrict__ Xcat,
                                                      const float* __restrict__ x,
                                                      const int* __restrict__ row_ptr,
                                                      const int* __restrict__ colS,
                                                      const float* __restrict__ dinv, int n) {
    int wid = (blockIdx.x * 256 + threadIdx.x) >> 6;
    int lane = threadIdx.x & 63;
    if (wid >= n) return;
    int e = row_ptr[wid], end = row_ptr[wid + 1];
    float a0 = 0.f, a1 = 0.f, b0 = 0.f, b1 = 0.f;
    for (; e + 1 < end; e += 2) {
        int c0 = colS[e], c1 = colS[e + 1];
        float w0 = dinv[c0], w1 = dinv[c1];
        unsigned p0 = *(const unsigned*)&Xcat[(size_t)c0 * K3 + 128 + lane * 2];
        unsigned p1 = *(const unsigned*)&Xcat[(size_t)c1 * K3 + 128 + lane * 2];
        a0 = fmaf(w0, bflo(p0), a0);
        a1 = fmaf(w0, bfhi(p0), a1);
        b0 = fmaf(w1, bflo(p1), b0);
        b1 = fmaf(w1, bfhi(p1), b1);
    }
    if (e < end) {
        int c0 = colS[e];
        float w0 = dinv[c0];
        unsigned p0 = *(const unsigned*)&Xcat[(size_t)c0 * K3 + 128 + lane * 2];
        a0 = fmaf(w0, bflo(p0), a0);
        a1 = fmaf(w0, bfhi(p0), a1);
    }
    float s = -2.f * dinv[wid];
    float2 xv = *(const float2*)&x[(size_t)wid * DIM + lane * 2];
    float o0 = fmaf(s, a0 + b0, -xv.x);
    float o1 = fmaf(s, a1 + b1, -xv.y);
    unsigned pk = ((unsigned)(unsigned short)f2bf(o1) << 16) | (unsigned short)f2bf(o0);
    *(unsigned*)&Xcat[(size_t)wid * K3 + 256 + lane * 2] = pk;
}

// ---------------- MFMA GEMM + bias + PReLU + fused channel stats ----------------
// grid (Mblocks, 2): block = 256 rows x 64 cols. 4 waves, wave = 64 rows x 64 cols.
__global__ __launch_bounds__(256) void gemm_mfma_kernel(const short* __restrict__ Xcat,
                                                        const short* __restrict__ WbT,
                                                        const float* __restrict__ bias,
                                                        const float* __restrict__ prelu_a,
                                                        float* __restrict__ out,
                                                        float* __restrict__ stats, int n) {
    __shared__ short wlds[64 * 392];
    __shared__ float sredS[4][64], sredQ[4][64];

    const int tid = threadIdx.x;
    const int jb = blockIdx.y;
    const int wid = tid >> 6, lane = tid & 63;
    const int g = lane >> 4, l15 = lane & 15;
    const int rbase = blockIdx.x * 256 + wid * 64;

    // stage WbT[jb*64 .. +63][0:384]: 3072 16B-chunks, 48 chunks per row
    #pragma unroll
    for (int c = 0; c < 12; ++c) {
        int chunk = tid + c * 256;           // 0..3071
        int row = chunk / 48, part = chunk % 48;
        *(short8*)&wlds[row * 392 + part * 8] =
            *(const short8*)&WbT[(size_t)(jb * 64 + row) * K3 + part * 8];
    }
    __syncthreads();

    const short* ap[4];
    #pragma unroll
    for (int ri = 0; ri < 4; ++ri) {
        int r = rbase + ri * 16 + l15;
        if (r >= n) r = n - 1;
        ap[ri] = Xcat + (size_t)r * K3 + g * 8;
    }

    f32x4 acc[4][4];
    #pragma unroll
    for (int ri = 0; ri < 4; ++ri)
        #pragma unroll
        for (int ci = 0; ci < 4; ++ci)
            acc[ri][ci] = (f32x4){0.f, 0.f, 0.f, 0.f};

    #pragma unroll
    for (int ks = 0; ks < 12; ++ks) {
        short8 a[4], b[4];
        #pragma unroll
        for (int ri = 0; ri < 4; ++ri)
            a[ri] = *(const short8*)(ap[ri] + ks * 32);
        #pragma unroll
        for (int ci = 0; ci < 4; ++ci)
            b[ci] = *(const short8*)&wlds[(ci * 16 + l15) * 392 + ks * 32 + g * 8];
        #pragma unroll
        for (int ri = 0; ri < 4; ++ri)
            #pragma unroll
            for (int ci = 0; ci < 4; ++ci)
                acc[ri][ci] = __builtin_amdgcn_mfma_f32_16x16x32_bf16(a[ri], b[ci],
                                                                      acc[ri][ci], 0, 0, 0);
    }

    const float ap_s = prelu_a[0];
    float bs[4];
    #pragma unroll
    for (int ci = 0; ci < 4; ++ci) bs[ci] = bias[jb * 64 + ci * 16 + l15];

    float sS[4] = {0.f, 0.f, 0.f, 0.f}, sQ[4] = {0.f, 0.f, 0.f, 0.f};
    #pragma unroll
    for (int ri = 0; ri < 4; ++ri) {
        #pragma unroll
        for (int ci = 0; ci < 4; ++ci) {
            int j = jb * 64 + ci * 16 + l15;
            #pragma unroll
            for (int reg = 0; reg < 4; ++reg) {
                int r = rbase + ri * 16 + 4 * g + reg;
                float v = acc[ri][ci][reg] + bs[ci];
                v = v > 0.f ? v : ap_s * v;
                if (r < n) {
                    out[(size_t)r * DIM + j] = v;
                } else {
                    v = 0.f;
                }
                sS[ci] += v;
                sQ[ci] += v * v;
            }
        }
    }
    #pragma unroll
    for (int ci = 0; ci < 4; ++ci) {
        sS[ci] += __shfl_xor(sS[ci], 16);
        sS[ci] += __shfl_xor(sS[ci], 32);
        sQ[ci] += __shfl_xor(sQ[ci], 16);
        sQ[ci] += __shfl_xor(sQ[ci], 32);
    }
    if (lane < 16) {
        #pragma unroll
        for (int ci = 0; ci < 4; ++ci) {
            sredS[wid][ci * 16 + l15] = sS[ci];
            sredQ[wid][ci * 16 + l15] = sQ[ci];
        }
    }
    __syncthreads();
    if (tid < 64) {
        float S = sredS[0][tid] + sredS[1][tid] + sredS[2][tid] + sredS[3][tid];
        float Q = sredQ[0][tid] + sredQ[1][tid] + sredQ[2][tid] + sredQ[3][tid];
        atomicAdd(&stats[jb * 64 + tid], S);
        atomicAdd(&stats[128 + jb * 64 + tid], Q);
    }
}

// ---------------- batchnorm ----------------
__global__ void bn_prep_kernel(float* __restrict__ stats, const float* __restrict__ gamma,
                               const float* __restrict__ beta, float invN) {
    int c = threadIdx.x;  // 128
    float mean = stats[c] * invN;
    float var = stats[128 + c] * invN - mean * mean;
    float sc = gamma[c] * rsqrtf(var + 1e-5f);
    stats[256 + c] = sc;
    stats[384 + c] = beta[c] - mean * sc;
}

__global__ __launch_bounds__(256) void bn_apply_kernel(float* __restrict__ out,
                                                       const float* __restrict__ scale,
                                                       const float* __restrict__ shift,
                                                       int total4) {
    int i0 = blockIdx.x * 256 + threadIdx.x;
    int stride = gridDim.x * 256;
    int c4 = i0 & 31;
    float4 sc = *(const float4*)&scale[c4 * 4];
    float4 sh = *(const float4*)&shift[c4 * 4];
    for (int i = i0; i < total4; i += stride) {
        float4 v = ((float4*)out)[i];
        v.x = v.x * sc.x + sh.x;
        v.y = v.y * sc.y + sh.y;
        v.z = v.z * sc.z + sh.z;
        v.w = v.w * sc.w + sh.w;
        ((float4*)out)[i] = v;
    }
}

extern "C" void kernel_launch(void* const* d_in, const int* in_sizes, int n_in,
                              void* d_out, int out_size, void* d_ws, size_t ws_size,
                              hipStream_t stream) {
    const float* x = (const float*)d_in[0];
    const int* ei = (const int*)d_in[1];
    const float* W = (const float*)d_in[2];
    const float* bias = (const float*)d_in[3];
    const float* prelu_a = (const float*)d_in[4];
    const float* gamma = (const float*)d_in[5];
    const float* beta = (const float*)d_in[6];
    float* out = (float*)d_out;

    const int N = in_sizes[0] / DIM;  // 100000
    const int E = in_sizes[1] / 2;    // 1600000
    const int* row = ei;
    const int* col = ei + E;

    char* ws = (char*)d_ws;
    size_t off = 0;
    auto take = [&](size_t bytes) {
        size_t p = off;
        off = (off + bytes + 1023) & ~(size_t)1023;
        return p;
    };
    int* deg       = (int*)(ws + take((size_t)N * 4));   // reused as cursor
    float* dinv    = (float*)(ws + take((size_t)N * 4));
    int* row_ptr   = (int*)(ws + take((size_t)(N + 1) * 4));
    int* blockSums = (int*)(ws + take(256 * 4));
    float* stats   = (float*)(ws + take(512 * 4));       // sum | sumsq | scale | shift
    int* colS      = (int*)(ws + take((size_t)E * 4));
    short* WbT     = (short*)(ws + take((size_t)DIM * K3 * 2));
    short* Xcat    = (short*)(ws + take((size_t)N * K3 * 2));

    (void)hipMemsetAsync(deg, 0, (size_t)N * 4, stream);
    (void)hipMemsetAsync(stats, 0, 512 * 4, stream);

    deg_kernel<<<(E + 255) / 256, 256, 0, stream>>>(row, deg, E);
    dinv_kernel<<<(N + 255) / 256, 256, 0, stream>>>(deg, dinv, N);

    int nb = (N + SCAN_ELEMS - 1) / SCAN_ELEMS;  // 98
    scan1_kernel<<<nb, SCAN_T, 0, stream>>>(deg, row_ptr, blockSums, N);
    scan2_kernel<<<1, 256, 0, stream>>>(blockSums, nb);
    scan3_kernel<<<(N + 255) / 256, 256, 0, stream>>>(row_ptr, blockSums, deg, N, E);
    fill_kernel<<<(E + 255) / 256, 256, 0, stream>>>(row, col, deg, colS, E);

    wbt_prep_kernel<<<DIM, 384, 0, stream>>>(W, WbT);
    convert_x_kernel<<<(N * 32 + 255) / 256, 256, 0, stream>>>(x, Xcat, N * 32);

    int gatherBlocks = (N * 64 + 255) / 256;
    gather1_kernel<<<gatherBlocks, 256, 0, stream>>>(Xcat, row_ptr, colS, dinv, N);
    gather2_kernel<<<gatherBlocks, 256, 0, stream>>>(Xcat, x, row_ptr, colS, dinv, N);

    dim3 ggrid((N + 255) / 256, 2);
    gemm_mfma_kernel<<<ggrid, 256, 0, stream>>>(Xcat, WbT, bias, prelu_a, out, stats, N);

    bn_prep_kernel<<<1, 128, 0, stream>>>(stats, gamma, beta, 1.0f / (float)N);
    bn_apply_kernel<<<2048, 256, 0, stream>>>(out, stats + 256, stats + 384, N * 32);
}

// Round 6
// 455.086 us; speedup vs baseline: 12.6121x; 1.0688x over previous
//
#include <hip/hip_runtime.h>

// ChebConv(K=3) + PReLU + BatchNorm, N=100000, E=1.6e6, 128->128.
// R6: fill uses atomicExch (allocating RMW, kills 16x write-through amp);
//     gathers 4-edge unrolled for MLP.

#define DIM 128
#define K3 384

typedef __attribute__((ext_vector_type(8))) short short8;
typedef __attribute__((ext_vector_type(4))) float f32x4;

__device__ __forceinline__ short f2bf(float f) {
    union { float f; unsigned u; } v{f};
    unsigned r = (v.u + 0x7FFF + ((v.u >> 16) & 1)) >> 16;  // RNE
    return (short)r;
}
__device__ __forceinline__ float bflo(unsigned p) {
    union { unsigned u; float f; } v{p << 16};
    return v.f;
}
__device__ __forceinline__ float bfhi(unsigned p) {
    union { unsigned u; float f; } v{p & 0xFFFF0000u};
    return v.f;
}

// ---------------- degree / dinv ----------------
__global__ __launch_bounds__(256) void deg_kernel(const int* __restrict__ row,
                                                  int* __restrict__ deg, int E) {
    int e = blockIdx.x * 256 + threadIdx.x;
    if (e < E) atomicAdd(&deg[row[e]], 1);
}

__global__ __launch_bounds__(256) void dinv_kernel(const int* __restrict__ deg,
                                                   float* __restrict__ dinv, int n) {
    int i = blockIdx.x * 256 + threadIdx.x;
    if (i < n) {
        int d = deg[i];
        dinv[i] = d > 0 ? rsqrtf((float)d) : 0.f;
    }
}

// ---------------- prefix scan ----------------
#define SCAN_T 256
#define SCAN_I 4
#define SCAN_ELEMS (SCAN_T * SCAN_I)

__global__ __launch_bounds__(SCAN_T) void scan1_kernel(const int* __restrict__ deg,
                                                       int* __restrict__ partial,
                                                       int* __restrict__ blockSums, int n) {
    __shared__ int lds[SCAN_T];
    int tbase = blockIdx.x * SCAN_ELEMS + threadIdx.x * SCAN_I;
    int v[SCAN_I];
    int tsum = 0;
    #pragma unroll
    for (int k = 0; k < SCAN_I; ++k) {
        int i = tbase + k;
        v[k] = (i < n) ? deg[i] : 0;
        tsum += v[k];
    }
    lds[threadIdx.x] = tsum;
    __syncthreads();
    int val = tsum;
    for (int off = 1; off < SCAN_T; off <<= 1) {
        int y = (threadIdx.x >= off) ? lds[threadIdx.x - off] : 0;
        __syncthreads();
        val += y;
        lds[threadIdx.x] = val;
        __syncthreads();
    }
    if (threadIdx.x == SCAN_T - 1) blockSums[blockIdx.x] = val;
    int run = val - tsum;
    #pragma unroll
    for (int k = 0; k < SCAN_I; ++k) {
        int i = tbase + k;
        if (i < n) partial[i] = run;
        run += v[k];
    }
}

__global__ __launch_bounds__(256) void scan2_kernel(int* __restrict__ blockSums, int nb) {
    __shared__ int lds[256];
    int v = (threadIdx.x < nb) ? blockSums[threadIdx.x] : 0;
    lds[threadIdx.x] = v;
    __syncthreads();
    int val = v;
    for (int off = 1; off < 256; off <<= 1) {
        int y = (threadIdx.x >= off) ? lds[threadIdx.x - off] : 0;
        __syncthreads();
        val += y;
        lds[threadIdx.x] = val;
        __syncthreads();
    }
    if (threadIdx.x < nb) blockSums[threadIdx.x] = val - v;
}

__global__ __launch_bounds__(256) void scan3_kernel(int* __restrict__ row_ptr,
                                                    const int* __restrict__ blockSums,
                                                    int* __restrict__ cursor, int n, int E) {
    int i = blockIdx.x * 256 + threadIdx.x;
    if (i < n) {
        int v = row_ptr[i] + blockSums[i / SCAN_ELEMS];
        row_ptr[i] = v;
        cursor[i] = v;
    }
    if (i == 0) row_ptr[n] = E;
}

// atomicExch instead of plain store: RMW allocates the line in cache, so the
// ~16 writes sharing each 64B colS line merge instead of each writing 64B to HBM.
__global__ __launch_bounds__(256) void fill_kernel(const int* __restrict__ row,
                                                   const int* __restrict__ col,
                                                   int* __restrict__ cursor,
                                                   int* __restrict__ colS, int E) {
    int e = blockIdx.x * 256 + threadIdx.x;
    if (e < E) {
        int pos = atomicAdd(&cursor[row[e]], 1);
        atomicExch(&colS[pos], col[e]);
    }
}

// ---------------- converts ----------------
__global__ __launch_bounds__(384) void wbt_prep_kernel(const float* __restrict__ W,
                                                       short* __restrict__ WbT) {
    int j = blockIdx.x;       // 0..127
    int kk = threadIdx.x;     // 0..383
    WbT[j * K3 + kk] = f2bf(W[kk * DIM + j]);
}

__global__ __launch_bounds__(256) void convert_x_kernel(const float* __restrict__ x,
                                                        short* __restrict__ Xcat, int n32) {
    int tid = blockIdx.x * 256 + threadIdx.x;
    if (tid >= n32) return;
    int i = tid >> 5, seg = tid & 31;
    float4 v = *(const float4*)&x[(size_t)i * DIM + seg * 4];
    short4 o;
    o.x = f2bf(v.x); o.y = f2bf(v.y); o.z = f2bf(v.z); o.w = f2bf(v.w);
    *(short4*)&Xcat[(size_t)i * K3 + seg * 4] = o;
}

// ---------------- gather propagation (bf16 in, bf16 out), 4-edge unrolled ----
__global__ __launch_bounds__(256) void gather1_kernel(short* __restrict__ Xcat,
                                                      const int* __restrict__ row_ptr,
                                                      const int* __restrict__ colS,
                                                      const float* __restrict__ dinv, int n) {
    int wid = (blockIdx.x * 256 + threadIdx.x) >> 6;
    int lane = threadIdx.x & 63;
    if (wid >= n) return;
    int e = row_ptr[wid], end = row_ptr[wid + 1];
    const int base = lane * 2;
    float a0 = 0.f, a1 = 0.f, b0 = 0.f, b1 = 0.f;
    float c0 = 0.f, c1 = 0.f, d0 = 0.f, d1 = 0.f;
    for (; e + 3 < end; e += 4) {
        int i0 = colS[e], i1 = colS[e + 1], i2 = colS[e + 2], i3 = colS[e + 3];
        float w0 = dinv[i0], w1 = dinv[i1], w2 = dinv[i2], w3 = dinv[i3];
        unsigned p0 = *(const unsigned*)&Xcat[(size_t)i0 * K3 + base];
        unsigned p1 = *(const unsigned*)&Xcat[(size_t)i1 * K3 + base];
        unsigned p2 = *(const unsigned*)&Xcat[(size_t)i2 * K3 + base];
        unsigned p3 = *(const unsigned*)&Xcat[(size_t)i3 * K3 + base];
        a0 = fmaf(w0, bflo(p0), a0); a1 = fmaf(w0, bfhi(p0), a1);
        b0 = fmaf(w1, bflo(p1), b0); b1 = fmaf(w1, bfhi(p1), b1);
        c0 = fmaf(w2, bflo(p2), c0); c1 = fmaf(w2, bfhi(p2), c1);
        d0 = fmaf(w3, bflo(p3), d0); d1 = fmaf(w3, bfhi(p3), d1);
    }
    for (; e < end; ++e) {
        int i0 = colS[e];
        float w0 = dinv[i0];
        unsigned p0 = *(const unsigned*)&Xcat[(size_t)i0 * K3 + base];
        a0 = fmaf(w0, bflo(p0), a0); a1 = fmaf(w0, bfhi(p0), a1);
    }
    float s = -dinv[wid];
    float o0 = s * ((a0 + b0) + (c0 + d0));
    float o1 = s * ((a1 + b1) + (c1 + d1));
    unsigned pk = ((unsigned)(unsigned short)f2bf(o1) << 16) | (unsigned short)f2bf(o0);
    *(unsigned*)&Xcat[(size_t)wid * K3 + 128 + base] = pk;
}

__global__ __launch_bounds__(256) void gather2_kernel(short* __restrict__ Xcat,
                                                      const float* __restrict__ x,
                                                      const int* __restrict__ row_ptr,
                                                      const int* __restrict__ colS,
                                                      const float* __restrict__ dinv, int n) {
    int wid = (blockIdx.x * 256 + threadIdx.x) >> 6;
    int lane = threadIdx.x & 63;
    if (wid >= n) return;
    int e = row_ptr[wid], end = row_ptr[wid + 1];
    const int base = lane * 2;
    float a0 = 0.f, a1 = 0.f, b0 = 0.f, b1 = 0.f;
    float c0 = 0.f, c1 = 0.f, d0 = 0.f, d1 = 0.f;
    for (; e + 3 < end; e += 4) {
        int i0 = colS[e], i1 = colS[e + 1], i2 = colS[e + 2], i3 = colS[e + 3];
        float w0 = dinv[i0], w1 = dinv[i1], w2 = dinv[i2], w3 = dinv[i3];
        unsigned p0 = *(const unsigned*)&Xcat[(size_t)i0 * K3 + 128 + base];
        unsigned p1 = *(const unsigned*)&Xcat[(size_t)i1 * K3 + 128 + base];
        unsigned p2 = *(const unsigned*)&Xcat[(size_t)i2 * K3 + 128 + base];
        unsigned p3 = *(const unsigned*)&Xcat[(size_t)i3 * K3 + 128 + base];
        a0 = fmaf(w0, bflo(p0), a0); a1 = fmaf(w0, bfhi(p0), a1);
        b0 = fmaf(w1, bflo(p1), b0); b1 = fmaf(w1, bfhi(p1), b1);
        c0 = fmaf(w2, bflo(p2), c0); c1 = fmaf(w2, bfhi(p2), c1);
        d0 = fmaf(w3, bflo(p3), d0); d1 = fmaf(w3, bfhi(p3), d1);
    }
    for (; e < end; ++e) {
        int i0 = colS[e];
        float w0 = dinv[i0];
        unsigned p0 = *(const unsigned*)&Xcat[(size_t)i0 * K3 + 128 + base];
        a0 = fmaf(w0, bflo(p0), a0); a1 = fmaf(w0, bfhi(p0), a1);
    }
    float s = -2.f * dinv[wid];
    float2 xv = *(const float2*)&x[(size_t)wid * DIM + base];
    float o0 = fmaf(s, (a0 + b0) + (c0 + d0), -xv.x);
    float o1 = fmaf(s, (a1 + b1) + (c1 + d1), -xv.y);
    unsigned pk = ((unsigned)(unsigned short)f2bf(o1) << 16) | (unsigned short)f2bf(o0);
    *(unsigned*)&Xcat[(size_t)wid * K3 + 256 + base] = pk;
}

// ---------------- MFMA GEMM + bias + PReLU + fused channel stats ----------------
__global__ __launch_bounds__(256) void gemm_mfma_kernel(const short* __restrict__ Xcat,
                                                        const short* __restrict__ WbT,
                                                        const float* __restrict__ bias,
                                                        const float* __restrict__ prelu_a,
                                                        float* __restrict__ out,
                                                        float* __restrict__ stats, int n) {
    __shared__ short wlds[64 * 392];
    __shared__ float sredS[4][64], sredQ[4][64];

    const int tid = threadIdx.x;
    const int jb = blockIdx.y;
    const int wid = tid >> 6, lane = tid & 63;
    const int g = lane >> 4, l15 = lane & 15;
    const int rbase = blockIdx.x * 256 + wid * 64;

    #pragma unroll
    for (int c = 0; c < 12; ++c) {
        int chunk = tid + c * 256;           // 0..3071
        int row = chunk / 48, part = chunk % 48;
        *(short8*)&wlds[row * 392 + part * 8] =
            *(const short8*)&WbT[(size_t)(jb * 64 + row) * K3 + part * 8];
    }
    __syncthreads();

    const short* ap[4];
    #pragma unroll
    for (int ri = 0; ri < 4; ++ri) {
        int r = rbase + ri * 16 + l15;
        if (r >= n) r = n - 1;
        ap[ri] = Xcat + (size_t)r * K3 + g * 8;
    }

    f32x4 acc[4][4];
    #pragma unroll
    for (int ri = 0; ri < 4; ++ri)
        #pragma unroll
        for (int ci = 0; ci < 4; ++ci)
            acc[ri][ci] = (f32x4){0.f, 0.f, 0.f, 0.f};

    #pragma unroll
    for (int ks = 0; ks < 12; ++ks) {
        short8 a[4], b[4];
        #pragma unroll
        for (int ri = 0; ri < 4; ++ri)
            a[ri] = *(const short8*)(ap[ri] + ks * 32);
        #pragma unroll
        for (int ci = 0; ci < 4; ++ci)
            b[ci] = *(const short8*)&wlds[(ci * 16 + l15) * 392 + ks * 32 + g * 8];
        #pragma unroll
        for (int ri = 0; ri < 4; ++ri)
            #pragma unroll
            for (int ci = 0; ci < 4; ++ci)
                acc[ri][ci] = __builtin_amdgcn_mfma_f32_16x16x32_bf16(a[ri], b[ci],
                                                                      acc[ri][ci], 0, 0, 0);
    }

    const float ap_s = prelu_a[0];
    float bs[4];
    #pragma unroll
    for (int ci = 0; ci < 4; ++ci) bs[ci] = bias[jb * 64 + ci * 16 + l15];

    float sS[4] = {0.f, 0.f, 0.f, 0.f}, sQ[4] = {0.f, 0.f, 0.f, 0.f};
    #pragma unroll
    for (int ri = 0; ri < 4; ++ri) {
        #pragma unroll
        for (int ci = 0; ci < 4; ++ci) {
            int j = jb * 64 + ci * 16 + l15;
            #pragma unroll
            for (int reg = 0; reg < 4; ++reg) {
                int r = rbase + ri * 16 + 4 * g + reg;
                float v = acc[ri][ci][reg] + bs[ci];
                v = v > 0.f ? v : ap_s * v;
                if (r < n) {
                    out[(size_t)r * DIM + j] = v;
                } else {
                    v = 0.f;
                }
                sS[ci] += v;
                sQ[ci] += v * v;
            }
        }
    }
    #pragma unroll
    for (int ci = 0; ci < 4; ++ci) {
        sS[ci] += __shfl_xor(sS[ci], 16);
        sS[ci] += __shfl_xor(sS[ci], 32);
        sQ[ci] += __shfl_xor(sQ[ci], 16);
        sQ[ci] += __shfl_xor(sQ[ci], 32);
    }
    if (lane < 16) {
        #pragma unroll
        for (int ci = 0; ci < 4; ++ci) {
            sredS[wid][ci * 16 + l15] = sS[ci];
            sredQ[wid][ci * 16 + l15] = sQ[ci];
        }
    }
    __syncthreads();
    if (tid < 64) {
        float S = sredS[0][tid] + sredS[1][tid] + sredS[2][tid] + sredS[3][tid];
        float Q = sredQ[0][tid] + sredQ[1][tid] + sredQ[2][tid] + sredQ[3][tid];
        atomicAdd(&stats[jb * 64 + tid], S);
        atomicAdd(&stats[128 + jb * 64 + tid], Q);
    }
}

// ---------------- batchnorm ----------------
__global__ void bn_prep_kernel(float* __restrict__ stats, const float* __restrict__ gamma,
                               const float* __restrict__ beta, float invN) {
    int c = threadIdx.x;  // 128
    float mean = stats[c] * invN;
    float var = stats[128 + c] * invN - mean * mean;
    float sc = gamma[c] * rsqrtf(var + 1e-5f);
    stats[256 + c] = sc;
    stats[384 + c] = beta[c] - mean * sc;
}

__global__ __launch_bounds__(256) void bn_apply_kernel(float* __restrict__ out,
                                                       const float* __restrict__ scale,
                                                       const float* __restrict__ shift,
                                                       int total4) {
    int i0 = blockIdx.x * 256 + threadIdx.x;
    int stride = gridDim.x * 256;
    int c4 = i0 & 31;
    float4 sc = *(const float4*)&scale[c4 * 4];
    float4 sh = *(const float4*)&shift[c4 * 4];
    for (int i = i0; i < total4; i += stride) {
        float4 v = ((float4*)out)[i];
        v.x = v.x * sc.x + sh.x;
        v.y = v.y * sc.y + sh.y;
        v.z = v.z * sc.z + sh.z;
        v.w = v.w * sc.w + sh.w;
        ((float4*)out)[i] = v;
    }
}

extern "C" void kernel_launch(void* const* d_in, const int* in_sizes, int n_in,
                              void* d_out, int out_size, void* d_ws, size_t ws_size,
                              hipStream_t stream) {
    const float* x = (const float*)d_in[0];
    const int* ei = (const int*)d_in[1];
    const float* W = (const float*)d_in[2];
    const float* bias = (const float*)d_in[3];
    const float* prelu_a = (const float*)d_in[4];
    const float* gamma = (const float*)d_in[5];
    const float* beta = (const float*)d_in[6];
    float* out = (float*)d_out;

    const int N = in_sizes[0] / DIM;  // 100000
    const int E = in_sizes[1] / 2;    // 1600000
    const int* row = ei;
    const int* col = ei + E;

    char* ws = (char*)d_ws;
    size_t off = 0;
    auto take = [&](size_t bytes) {
        size_t p = off;
        off = (off + bytes + 1023) & ~(size_t)1023;
        return p;
    };
    int* deg       = (int*)(ws + take((size_t)N * 4));   // reused as cursor
    float* dinv    = (float*)(ws + take((size_t)N * 4));
    int* row_ptr   = (int*)(ws + take((size_t)(N + 1) * 4));
    int* blockSums = (int*)(ws + take(256 * 4));
    float* stats   = (float*)(ws + take(512 * 4));       // sum | sumsq | scale | shift
    int* colS      = (int*)(ws + take((size_t)E * 4));
    short* WbT     = (short*)(ws + take((size_t)DIM * K3 * 2));
    short* Xcat    = (short*)(ws + take((size_t)N * K3 * 2));

    (void)hipMemsetAsync(deg, 0, (size_t)N * 4, stream);
    (void)hipMemsetAsync(stats, 0, 512 * 4, stream);

    deg_kernel<<<(E + 255) / 256, 256, 0, stream>>>(row, deg, E);
    dinv_kernel<<<(N + 255) / 256, 256, 0, stream>>>(deg, dinv, N);

    int nb = (N + SCAN_ELEMS - 1) / SCAN_ELEMS;  // 98
    scan1_kernel<<<nb, SCAN_T, 0, stream>>>(deg, row_ptr, blockSums, N);
    scan2_kernel<<<1, 256, 0, stream>>>(blockSums, nb);
    scan3_kernel<<<(N + 255) / 256, 256, 0, stream>>>(row_ptr, blockSums, deg, N, E);
    fill_kernel<<<(E + 255) / 256, 256, 0, stream>>>(row, col, deg, colS, E);

    wbt_prep_kernel<<<DIM, 384, 0, stream>>>(W, WbT);
    convert_x_kernel<<<(N * 32 + 255) / 256, 256, 0, stream>>>(x, Xcat, N * 32);

    int gatherBlocks = (N * 64 + 255) / 256;
    gather1_kernel<<<gatherBlocks, 256, 0, stream>>>(Xcat, row_ptr, colS, dinv, N);
    gather2_kernel<<<gatherBlocks, 256, 0, stream>>>(Xcat, x, row_ptr, colS, dinv, N);

    dim3 ggrid((N + 255) / 256, 2);
    gemm_mfma_kernel<<<ggrid, 256, 0, stream>>>(Xcat, WbT, bias, prelu_a, out, stats, N);

    bn_prep_kernel<<<1, 128, 0, stream>>>(stats, gamma, beta, 1.0f / (float)N);
    bn_apply_kernel<<<2048, 256, 0, stream>>>(out, stats + 256, stats + 384, N * 32);
}

// Round 7
// 440.554 us; speedup vs baseline: 13.0281x; 1.0330x over previous
//
#include <hip/hip_runtime.h>

// ChebConv(K=3) + PReLU + BatchNorm, N=100000, E=1.6e6, 128->128.
// R7: fill/deg process 4 edges/thread (4 independent atomic chains -> 4x MLP);
//     fill back to plain store (atomicExch was -10%); gather2 reads bf16 x.

#define DIM 128
#define K3 384

typedef __attribute__((ext_vector_type(8))) short short8;
typedef __attribute__((ext_vector_type(4))) float f32x4;

__device__ __forceinline__ short f2bf(float f) {
    union { float f; unsigned u; } v{f};
    unsigned r = (v.u + 0x7FFF + ((v.u >> 16) & 1)) >> 16;  // RNE
    return (short)r;
}
__device__ __forceinline__ float bflo(unsigned p) {
    union { unsigned u; float f; } v{p << 16};
    return v.f;
}
__device__ __forceinline__ float bfhi(unsigned p) {
    union { unsigned u; float f; } v{p & 0xFFFF0000u};
    return v.f;
}

// ---------------- degree / dinv (4 edges per thread) ----------------
__global__ __launch_bounds__(256) void deg_kernel(const int* __restrict__ row,
                                                  int* __restrict__ deg, int E) {
    int t = blockIdx.x * 256 + threadIdx.x;
    int e0 = t * 4;
    if (e0 + 3 < E) {
        int4 r = *(const int4*)&row[e0];
        atomicAdd(&deg[r.x], 1);
        atomicAdd(&deg[r.y], 1);
        atomicAdd(&deg[r.z], 1);
        atomicAdd(&deg[r.w], 1);
    } else {
        for (int e = e0; e < E; ++e) atomicAdd(&deg[row[e]], 1);
    }
}

__global__ __launch_bounds__(256) void dinv_kernel(const int* __restrict__ deg,
                                                   float* __restrict__ dinv, int n) {
    int i = blockIdx.x * 256 + threadIdx.x;
    if (i < n) {
        int d = deg[i];
        dinv[i] = d > 0 ? rsqrtf((float)d) : 0.f;
    }
}

// ---------------- prefix scan ----------------
#define SCAN_T 256
#define SCAN_I 4
#define SCAN_ELEMS (SCAN_T * SCAN_I)

__global__ __launch_bounds__(SCAN_T) void scan1_kernel(const int* __restrict__ deg,
                                                       int* __restrict__ partial,
                                                       int* __restrict__ blockSums, int n) {
    __shared__ int lds[SCAN_T];
    int tbase = blockIdx.x * SCAN_ELEMS + threadIdx.x * SCAN_I;
    int v[SCAN_I];
    int tsum = 0;
    #pragma unroll
    for (int k = 0; k < SCAN_I; ++k) {
        int i = tbase + k;
        v[k] = (i < n) ? deg[i] : 0;
        tsum += v[k];
    }
    lds[threadIdx.x] = tsum;
    __syncthreads();
    int val = tsum;
    for (int off = 1; off < SCAN_T; off <<= 1) {
        int y = (threadIdx.x >= off) ? lds[threadIdx.x - off] : 0;
        __syncthreads();
        val += y;
        lds[threadIdx.x] = val;
        __syncthreads();
    }
    if (threadIdx.x == SCAN_T - 1) blockSums[blockIdx.x] = val;
    int run = val - tsum;
    #pragma unroll
    for (int k = 0; k < SCAN_I; ++k) {
        int i = tbase + k;
        if (i < n) partial[i] = run;
        run += v[k];
    }
}

__global__ __launch_bounds__(256) void scan2_kernel(int* __restrict__ blockSums, int nb) {
    __shared__ int lds[256];
    int v = (threadIdx.x < nb) ? blockSums[threadIdx.x] : 0;
    lds[threadIdx.x] = v;
    __syncthreads();
    int val = v;
    for (int off = 1; off < 256; off <<= 1) {
        int y = (threadIdx.x >= off) ? lds[threadIdx.x - off] : 0;
        __syncthreads();
        val += y;
        lds[threadIdx.x] = val;
        __syncthreads();
    }
    if (threadIdx.x < nb) blockSums[threadIdx.x] = val - v;
}

__global__ __launch_bounds__(256) void scan3_kernel(int* __restrict__ row_ptr,
                                                    const int* __restrict__ blockSums,
                                                    int* __restrict__ cursor, int n, int E) {
    int i = blockIdx.x * 256 + threadIdx.x;
    if (i < n) {
        int v = row_ptr[i] + blockSums[i / SCAN_ELEMS];
        row_ptr[i] = v;
        cursor[i] = v;
    }
    if (i == 0) row_ptr[n] = E;
}

// 4 edges per thread: 4 independent atomicAdd->store chains in flight.
__global__ __launch_bounds__(256) void fill_kernel(const int* __restrict__ row,
                                                   const int* __restrict__ col,
                                                   int* __restrict__ cursor,
                                                   int* __restrict__ colS, int E) {
    int t = blockIdx.x * 256 + threadIdx.x;
    int e0 = t * 4;
    if (e0 + 3 < E) {
        int4 r = *(const int4*)&row[e0];
        int4 c = *(const int4*)&col[e0];
        int p0 = atomicAdd(&cursor[r.x], 1);
        int p1 = atomicAdd(&cursor[r.y], 1);
        int p2 = atomicAdd(&cursor[r.z], 1);
        int p3 = atomicAdd(&cursor[r.w], 1);
        colS[p0] = c.x;
        colS[p1] = c.y;
        colS[p2] = c.z;
        colS[p3] = c.w;
    } else {
        for (int e = e0; e < E; ++e) {
            int pos = atomicAdd(&cursor[row[e]], 1);
            colS[pos] = col[e];
        }
    }
}

// ---------------- converts ----------------
__global__ __launch_bounds__(384) void wbt_prep_kernel(const float* __restrict__ W,
                                                       short* __restrict__ WbT) {
    int j = blockIdx.x;       // 0..127
    int kk = threadIdx.x;     // 0..383
    WbT[j * K3 + kk] = f2bf(W[kk * DIM + j]);
}

__global__ __launch_bounds__(256) void convert_x_kernel(const float* __restrict__ x,
                                                        short* __restrict__ Xcat, int n32) {
    int tid = blockIdx.x * 256 + threadIdx.x;
    if (tid >= n32) return;
    int i = tid >> 5, seg = tid & 31;
    float4 v = *(const float4*)&x[(size_t)i * DIM + seg * 4];
    short4 o;
    o.x = f2bf(v.x); o.y = f2bf(v.y); o.z = f2bf(v.z); o.w = f2bf(v.w);
    *(short4*)&Xcat[(size_t)i * K3 + seg * 4] = o;
}

// ---------------- gather propagation (bf16 in, bf16 out), 4-edge unrolled ----
__global__ __launch_bounds__(256) void gather1_kernel(short* __restrict__ Xcat,
                                                      const int* __restrict__ row_ptr,
                                                      const int* __restrict__ colS,
                                                      const float* __restrict__ dinv, int n) {
    int wid = (blockIdx.x * 256 + threadIdx.x) >> 6;
    int lane = threadIdx.x & 63;
    if (wid >= n) return;
    int e = row_ptr[wid], end = row_ptr[wid + 1];
    const int base = lane * 2;
    float a0 = 0.f, a1 = 0.f, b0 = 0.f, b1 = 0.f;
    float c0 = 0.f, c1 = 0.f, d0 = 0.f, d1 = 0.f;
    for (; e + 3 < end; e += 4) {
        int i0 = colS[e], i1 = colS[e + 1], i2 = colS[e + 2], i3 = colS[e + 3];
        float w0 = dinv[i0], w1 = dinv[i1], w2 = dinv[i2], w3 = dinv[i3];
        unsigned p0 = *(const unsigned*)&Xcat[(size_t)i0 * K3 + base];
        unsigned p1 = *(const unsigned*)&Xcat[(size_t)i1 * K3 + base];
        unsigned p2 = *(const unsigned*)&Xcat[(size_t)i2 * K3 + base];
        unsigned p3 = *(const unsigned*)&Xcat[(size_t)i3 * K3 + base];
        a0 = fmaf(w0, bflo(p0), a0); a1 = fmaf(w0, bfhi(p0), a1);
        b0 = fmaf(w1, bflo(p1), b0); b1 = fmaf(w1, bfhi(p1), b1);
        c0 = fmaf(w2, bflo(p2), c0); c1 = fmaf(w2, bfhi(p2), c1);
        d0 = fmaf(w3, bflo(p3), d0); d1 = fmaf(w3, bfhi(p3), d1);
    }
    for (; e < end; ++e) {
        int i0 = colS[e];
        float w0 = dinv[i0];
        unsigned p0 = *(const unsigned*)&Xcat[(size_t)i0 * K3 + base];
        a0 = fmaf(w0, bflo(p0), a0); a1 = fmaf(w0, bfhi(p0), a1);
    }
    float s = -dinv[wid];
    float o0 = s * ((a0 + b0) + (c0 + d0));
    float o1 = s * ((a1 + b1) + (c1 + d1));
    unsigned pk = ((unsigned)(unsigned short)f2bf(o1) << 16) | (unsigned short)f2bf(o0);
    *(unsigned*)&Xcat[(size_t)wid * K3 + 128 + base] = pk;
}

__global__ __launch_bounds__(256) void gather2_kernel(short* __restrict__ Xcat,
                                                      const int* __restrict__ row_ptr,
                                                      const int* __restrict__ colS,
                                                      const float* __restrict__ dinv, int n) {
    int wid = (blockIdx.x * 256 + threadIdx.x) >> 6;
    int lane = threadIdx.x & 63;
    if (wid >= n) return;
    int e = row_ptr[wid], end = row_ptr[wid + 1];
    const int base = lane * 2;
    float a0 = 0.f, a1 = 0.f, b0 = 0.f, b1 = 0.f;
    float c0 = 0.f, c1 = 0.f, d0 = 0.f, d1 = 0.f;
    for (; e + 3 < end; e += 4) {
        int i0 = colS[e], i1 = colS[e + 1], i2 = colS[e + 2], i3 = colS[e + 3];
        float w0 = dinv[i0], w1 = dinv[i1], w2 = dinv[i2], w3 = dinv[i3];
        unsigned p0 = *(const unsigned*)&Xcat[(size_t)i0 * K3 + 128 + base];
        unsigned p1 = *(const unsigned*)&Xcat[(size_t)i1 * K3 + 128 + base];
        unsigned p2 = *(const unsigned*)&Xcat[(size_t)i2 * K3 + 128 + base];
        unsigned p3 = *(const unsigned*)&Xcat[(size_t)i3 * K3 + 128 + base];
        a0 = fmaf(w0, bflo(p0), a0); a1 = fmaf(w0, bfhi(p0), a1);
        b0 = fmaf(w1, bflo(p1), b0); b1 = fmaf(w1, bfhi(p1), b1);
        c0 = fmaf(w2, bflo(p2), c0); c1 = fmaf(w2, bfhi(p2), c1);
        d0 = fmaf(w3, bflo(p3), d0); d1 = fmaf(w3, bfhi(p3), d1);
    }
    for (; e < end; ++e) {
        int i0 = colS[e];
        float w0 = dinv[i0];
        unsigned p0 = *(const unsigned*)&Xcat[(size_t)i0 * K3 + 128 + base];
        a0 = fmaf(w0, bflo(p0), a0); a1 = fmaf(w0, bfhi(p0), a1);
    }
    float s = -2.f * dinv[wid];
    unsigned px = *(const unsigned*)&Xcat[(size_t)wid * K3 + base];  // bf16 x row
    float o0 = fmaf(s, (a0 + b0) + (c0 + d0), -bflo(px));
    float o1 = fmaf(s, (a1 + b1) + (c1 + d1), -bfhi(px));
    unsigned pk = ((unsigned)(unsigned short)f2bf(o1) << 16) | (unsigned short)f2bf(o0);
    *(unsigned*)&Xcat[(size_t)wid * K3 + 256 + base] = pk;
}

// ---------------- MFMA GEMM + bias + PReLU + fused channel stats ----------------
__global__ __launch_bounds__(256) void gemm_mfma_kernel(const short* __restrict__ Xcat,
                                                        const short* __restrict__ WbT,
                                                        const float* __restrict__ bias,
                                                        const float* __restrict__ prelu_a,
                                                        float* __restrict__ out,
                                                        float* __restrict__ stats, int n) {
    __shared__ short wlds[64 * 392];
    __shared__ float sredS[4][64], sredQ[4][64];

    const int tid = threadIdx.x;
    const int jb = blockIdx.y;
    const int wid = tid >> 6, lane = tid & 63;
    const int g = lane >> 4, l15 = lane & 15;
    const int rbase = blockIdx.x * 256 + wid * 64;

    #pragma unroll
    for (int c = 0; c < 12; ++c) {
        int chunk = tid + c * 256;           // 0..3071
        int row = chunk / 48, part = chunk % 48;
        *(short8*)&wlds[row * 392 + part * 8] =
            *(const short8*)&WbT[(size_t)(jb * 64 + row) * K3 + part * 8];
    }
    __syncthreads();

    const short* ap[4];
    #pragma unroll
    for (int ri = 0; ri < 4; ++ri) {
        int r = rbase + ri * 16 + l15;
        if (r >= n) r = n - 1;
        ap[ri] = Xcat + (size_t)r * K3 + g * 8;
    }

    f32x4 acc[4][4];
    #pragma unroll
    for (int ri = 0; ri < 4; ++ri)
        #pragma unroll
        for (int ci = 0; ci < 4; ++ci)
            acc[ri][ci] = (f32x4){0.f, 0.f, 0.f, 0.f};

    #pragma unroll
    for (int ks = 0; ks < 12; ++ks) {
        short8 a[4], b[4];
        #pragma unroll
        for (int ri = 0; ri < 4; ++ri)
            a[ri] = *(const short8*)(ap[ri] + ks * 32);
        #pragma unroll
        for (int ci = 0; ci < 4; ++ci)
            b[ci] = *(const short8*)&wlds[(ci * 16 + l15) * 392 + ks * 32 + g * 8];
        #pragma unroll
        for (int ri = 0; ri < 4; ++ri)
            #pragma unroll
            for (int ci = 0; ci < 4; ++ci)
                acc[ri][ci] = __builtin_amdgcn_mfma_f32_16x16x32_bf16(a[ri], b[ci],
                                                                      acc[ri][ci], 0, 0, 0);
    }

    const float ap_s = prelu_a[0];
    float bs[4];
    #pragma unroll
    for (int ci = 0; ci < 4; ++ci) bs[ci] = bias[jb * 64 + ci * 16 + l15];

    float sS[4] = {0.f, 0.f, 0.f, 0.f}, sQ[4] = {0.f, 0.f, 0.f, 0.f};
    #pragma unroll
    for (int ri = 0; ri < 4; ++ri) {
        #pragma unroll
        for (int ci = 0; ci < 4; ++ci) {
            int j = jb * 64 + ci * 16 + l15;
            #pragma unroll
            for (int reg = 0; reg < 4; ++reg) {
                int r = rbase + ri * 16 + 4 * g + reg;
                float v = acc[ri][ci][reg] + bs[ci];
                v = v > 0.f ? v : ap_s * v;
                if (r < n) {
                    out[(size_t)r * DIM + j] = v;
                } else {
                    v = 0.f;
                }
                sS[ci] += v;
                sQ[ci] += v * v;
            }
        }
    }
    #pragma unroll
    for (int ci = 0; ci < 4; ++ci) {
        sS[ci] += __shfl_xor(sS[ci], 16);
        sS[ci] += __shfl_xor(sS[ci], 32);
        sQ[ci] += __shfl_xor(sQ[ci], 16);
        sQ[ci] += __shfl_xor(sQ[ci], 32);
    }
    if (lane < 16) {
        #pragma unroll
        for (int ci = 0; ci < 4; ++ci) {
            sredS[wid][ci * 16 + l15] = sS[ci];
            sredQ[wid][ci * 16 + l15] = sQ[ci];
        }
    }
    __syncthreads();
    if (tid < 64) {
        float S = sredS[0][tid] + sredS[1][tid] + sredS[2][tid] + sredS[3][tid];
        float Q = sredQ[0][tid] + sredQ[1][tid] + sredQ[2][tid] + sredQ[3][tid];
        atomicAdd(&stats[jb * 64 + tid], S);
        atomicAdd(&stats[128 + jb * 64 + tid], Q);
    }
}

// ---------------- batchnorm ----------------
__global__ void bn_prep_kernel(float* __restrict__ stats, const float* __restrict__ gamma,
                               const float* __restrict__ beta, float invN) {
    int c = threadIdx.x;  // 128
    float mean = stats[c] * invN;
    float var = stats[128 + c] * invN - mean * mean;
    float sc = gamma[c] * rsqrtf(var + 1e-5f);
    stats[256 + c] = sc;
    stats[384 + c] = beta[c] - mean * sc;
}

__global__ __launch_bounds__(256) void bn_apply_kernel(float* __restrict__ out,
                                                       const float* __restrict__ scale,
                                                       const float* __restrict__ shift,
                                                       int total4) {
    int i0 = blockIdx.x * 256 + threadIdx.x;
    int stride = gridDim.x * 256;
    int c4 = i0 & 31;
    float4 sc = *(const float4*)&scale[c4 * 4];
    float4 sh = *(const float4*)&shift[c4 * 4];
    for (int i = i0; i < total4; i += stride) {
        float4 v = ((float4*)out)[i];
        v.x = v.x * sc.x + sh.x;
        v.y = v.y * sc.y + sh.y;
        v.z = v.z * sc.z + sh.z;
        v.w = v.w * sc.w + sh.w;
        ((float4*)out)[i] = v;
    }
}

extern "C" void kernel_launch(void* const* d_in, const int* in_sizes, int n_in,
                              void* d_out, int out_size, void* d_ws, size_t ws_size,
                              hipStream_t stream) {
    const float* x = (const float*)d_in[0];
    const int* ei = (const int*)d_in[1];
    const float* W = (const float*)d_in[2];
    const float* bias = (const float*)d_in[3];
    const float* prelu_a = (const float*)d_in[4];
    const float* gamma = (const float*)d_in[5];
    const float* beta = (const float*)d_in[6];
    float* out = (float*)d_out;

    const int N = in_sizes[0] / DIM;  // 100000
    const int E = in_sizes[1] / 2;    // 1600000
    const int* row = ei;
    const int* col = ei + E;

    char* ws = (char*)d_ws;
    size_t off = 0;
    auto take = [&](size_t bytes) {
        size_t p = off;
        off = (off + bytes + 1023) & ~(size_t)1023;
        return p;
    };
    int* deg       = (int*)(ws + take((size_t)N * 4));   // reused as cursor
    float* dinv    = (float*)(ws + take((size_t)N * 4));
    int* row_ptr   = (int*)(ws + take((size_t)(N + 1) * 4));
    int* blockSums = (int*)(ws + take(256 * 4));
    float* stats   = (float*)(ws + take(512 * 4));       // sum | sumsq | scale | shift
    int* colS      = (int*)(ws + take((size_t)E * 4));
    short* WbT     = (short*)(ws + take((size_t)DIM * K3 * 2));
    short* Xcat    = (short*)(ws + take((size_t)N * K3 * 2));

    (void)hipMemsetAsync(deg, 0, (size_t)N * 4, stream);
    (void)hipMemsetAsync(stats, 0, 512 * 4, stream);

    deg_kernel<<<(E / 4 + 255) / 256, 256, 0, stream>>>(row, deg, E);
    dinv_kernel<<<(N + 255) / 256, 256, 0, stream>>>(deg, dinv, N);

    int nb = (N + SCAN_ELEMS - 1) / SCAN_ELEMS;  // 98
    scan1_kernel<<<nb, SCAN_T, 0, stream>>>(deg, row_ptr, blockSums, N);
    scan2_kernel<<<1, 256, 0, stream>>>(blockSums, nb);
    scan3_kernel<<<(N + 255) / 256, 256, 0, stream>>>(row_ptr, blockSums, deg, N, E);
    fill_kernel<<<(E / 4 + 255) / 256, 256, 0, stream>>>(row, col, deg, colS, E);

    wbt_prep_kernel<<<DIM, 384, 0, stream>>>(W, WbT);
    convert_x_kernel<<<(N * 32 + 255) / 256, 256, 0, stream>>>(x, Xcat, N * 32);

    int gatherBlocks = (N * 64 + 255) / 256;
    gather1_kernel<<<gatherBlocks, 256, 0, stream>>>(Xcat, row_ptr, colS, dinv, N);
    gather2_kernel<<<gatherBlocks, 256, 0, stream>>>(Xcat, row_ptr, colS, dinv, N);

    dim3 ggrid((N + 255) / 256, 2);
    gemm_mfma_kernel<<<ggrid, 256, 0, stream>>>(Xcat, WbT, bias, prelu_a, out, stats, N);

    bn_prep_kernel<<<1, 128, 0, stream>>>(stats, gamma, beta, 1.0f / (float)N);
    bn_apply_kernel<<<2048, 256, 0, stream>>>(out, stats + 256, stats + 384, N * 32);
}

// Round 8
// 281.338 us; speedup vs baseline: 20.4011x; 1.5659x over previous
//
#include <hip/hip_runtime.h>

// ChebConv(K=3) + PReLU + BatchNorm, N=100000, E=1.6e6, 128->128.
// R8: CSR build via deterministic two-level counting sort (no global atomics,
//     full-line writes). Replaces deg/dinv/row-scan/fill.

#define DIM 128
#define K3 384
#define CHUNK 3200      // edges per bin block
#define SEGCAP 6400     // max packed ints per bucket staged in LDS (mean 4096)

typedef __attribute__((ext_vector_type(8))) short short8;
typedef __attribute__((ext_vector_type(4))) float f32x4;

__device__ __forceinline__ short f2bf(float f) {
    union { float f; unsigned u; } v{f};
    unsigned r = (v.u + 0x7FFF + ((v.u >> 16) & 1)) >> 16;  // RNE
    return (short)r;
}
__device__ __forceinline__ float bflo(unsigned p) {
    union { unsigned u; float f; } v{p << 16};
    return v.f;
}
__device__ __forceinline__ float bfhi(unsigned p) {
    union { unsigned u; float f; } v{p & 0xFFFF0000u};
    return v.f;
}

// ---------------- K1: per-block bucket binning (buckets = row>>8) ----------------
// Out: pairsLocal[blk*CHUNK + i] = block's edges sorted by bucket, packed
//      (rowlocal<<17)|col ; M[b*NBLK+blk] = count ; localPtr[blk*NBUCK+b] = local excl.
__global__ __launch_bounds__(256) void bin_kernel(const int* __restrict__ row,
                                                  const int* __restrict__ col,
                                                  int* __restrict__ M,
                                                  int* __restrict__ localPtr,
                                                  int* __restrict__ pairsLocal,
                                                  int E, int NBLK, int NBUCK) {
    __shared__ int hist[512];
    __shared__ int sA[512], sB[512];
    __shared__ int cur[512];
    __shared__ int staged[CHUNK];
    const int tid = threadIdx.x, blk = blockIdx.x;
    const int base = blk * CHUNK;
    int vt = E - base;
    if (vt > CHUNK) vt = CHUNK;
    if (vt < 0) vt = 0;

    hist[tid] = 0;
    hist[tid + 256] = 0;
    __syncthreads();
    for (int t = tid; t < vt; t += 256) atomicAdd(&hist[row[base + t] >> 8], 1);
    __syncthreads();

    for (int b = tid; b < NBUCK; b += 256) M[b * NBLK + blk] = hist[b];

    // inclusive Hillis-Steele over 512 (2 elems/thread, double-buffered)
    sA[tid] = hist[tid];
    sA[tid + 256] = hist[tid + 256];
    __syncthreads();
    int* src = sA;
    int* dst = sB;
    for (int off = 1; off < 512; off <<= 1) {
        #pragma unroll
        for (int k = 0; k < 2; ++k) {
            int i = tid + k * 256;
            int v = src[i];
            if (i >= off) v += src[i - off];
            dst[i] = v;
        }
        __syncthreads();
        int* tmp = src; src = dst; dst = tmp;
    }
    #pragma unroll
    for (int k = 0; k < 2; ++k) {
        int i = tid + k * 256;
        int ex = (i == 0) ? 0 : src[i - 1];
        cur[i] = ex;
        if (i < NBUCK) localPtr[blk * NBUCK + i] = ex;
    }
    __syncthreads();

    for (int t = tid; t < vt; t += 256) {
        int r = row[base + t], c = col[base + t];
        int pos = atomicAdd(&cur[r >> 8], 1);   // LDS atomic
        staged[pos] = ((r & 255) << 17) | c;
    }
    __syncthreads();
    for (int t = tid; t < vt; t += 256) pairsLocal[base + t] = staged[t];
}

// ---------------- K2: flat exclusive scan of M (n = NBUCK*NBLK) ----------------
#define SCAN_T 256
#define SCAN_I 4
#define SCAN_ELEMS (SCAN_T * SCAN_I)

__global__ __launch_bounds__(SCAN_T) void scan1_kernel(const int* __restrict__ in,
                                                       int* __restrict__ out,
                                                       int* __restrict__ blockSums, int n) {
    __shared__ int lds[SCAN_T];
    int tbase = blockIdx.x * SCAN_ELEMS + threadIdx.x * SCAN_I;
    int v[SCAN_I];
    int tsum = 0;
    #pragma unroll
    for (int k = 0; k < SCAN_I; ++k) {
        int i = tbase + k;
        v[k] = (i < n) ? in[i] : 0;
        tsum += v[k];
    }
    lds[threadIdx.x] = tsum;
    __syncthreads();
    int val = tsum;
    for (int off = 1; off < SCAN_T; off <<= 1) {
        int y = (threadIdx.x >= off) ? lds[threadIdx.x - off] : 0;
        __syncthreads();
        val += y;
        lds[threadIdx.x] = val;
        __syncthreads();
    }
    if (threadIdx.x == SCAN_T - 1) blockSums[blockIdx.x] = val;
    int run = val - tsum;
    #pragma unroll
    for (int k = 0; k < SCAN_I; ++k) {
        int i = tbase + k;
        if (i < n) out[i] = run;
        run += v[k];
    }
}

__global__ __launch_bounds__(256) void scan2_kernel(int* __restrict__ blockSums, int nb) {
    __shared__ int lds[256];
    int v = (threadIdx.x < nb) ? blockSums[threadIdx.x] : 0;
    lds[threadIdx.x] = v;
    __syncthreads();
    int val = v;
    for (int off = 1; off < 256; off <<= 1) {
        int y = (threadIdx.x >= off) ? lds[threadIdx.x - off] : 0;
        __syncthreads();
        val += y;
        lds[threadIdx.x] = val;
        __syncthreads();
    }
    if (threadIdx.x < nb) blockSums[threadIdx.x] = val - v;
}

__global__ __launch_bounds__(256) void scan3_kernel(int* __restrict__ out,
                                                    const int* __restrict__ blockSums,
                                                    int n, int total) {
    int i = blockIdx.x * 256 + threadIdx.x;
    if (i < n) out[i] += blockSums[i / SCAN_ELEMS];
    if (i == 0) out[n] = total;  // sentinel
}

// ---------------- K3: per-bucket CSR build in LDS ----------------
__global__ __launch_bounds__(256) void csr_kernel(const int* __restrict__ Ms,
                                                  const int* __restrict__ localPtr,
                                                  const int* __restrict__ pairsLocal,
                                                  int* __restrict__ row_ptr,
                                                  float* __restrict__ dinv,
                                                  int* __restrict__ colS,
                                                  int E, int N, int NBLK, int NBUCK) {
    __shared__ int seg[SEGCAP];
    __shared__ int cls[SEGCAP];
    __shared__ int crcnt[256], scA[256], scB[256], cur[256];
    const int tid = threadIdx.x, b = blockIdx.x;
    const int fb = b * NBLK;
    const int bstart = Ms[fb];
    const int bend = Ms[fb + NBLK];
    int sz = bend - bstart;
    if (sz > SEGCAP) sz = SEGCAP;  // safety clamp (binomial max ~4500 << 6400)

    // gather this bucket's segment from each bin block
    for (int blk = tid; blk < NBLK; blk += 256) {
        int f = fb + blk;
        int s = Ms[f];
        int cnt = Ms[f + 1] - s;
        int d0 = s - bstart;
        int srcp = blk * CHUNK + localPtr[blk * NBUCK + b];
        for (int k = 0; k < cnt; ++k) {
            int d = d0 + k;
            if (d < SEGCAP) seg[d] = pairsLocal[srcp + k];
        }
    }
    crcnt[tid] = 0;
    __syncthreads();

    for (int i = tid; i < sz; i += 256) atomicAdd(&crcnt[seg[i] >> 17], 1);
    __syncthreads();

    // inclusive scan of 256 row counts
    scA[tid] = crcnt[tid];
    __syncthreads();
    int* src = scA;
    int* dst = scB;
    for (int off = 1; off < 256; off <<= 1) {
        int v = src[tid];
        if (tid >= off) v += src[tid - off];
        dst[tid] = v;
        __syncthreads();
        int* tmp = src; src = dst; dst = tmp;
    }
    int excl = (tid == 0) ? 0 : src[tid - 1];
    cur[tid] = excl;
    int gr = (b << 8) + tid;
    if (gr < N) {
        row_ptr[gr] = bstart + excl;
        int d = crcnt[tid];
        dinv[gr] = d > 0 ? rsqrtf((float)d) : 0.f;
    }
    if (b == 0 && tid == 0) row_ptr[N] = E;
    __syncthreads();

    for (int i = tid; i < sz; i += 256) {
        int p = seg[i];
        int pos = atomicAdd(&cur[p >> 17], 1);  // LDS atomic
        cls[pos] = p & 0x1FFFF;
    }
    __syncthreads();
    for (int i = tid; i < sz; i += 256) colS[bstart + i] = cls[i];
}

// ---------------- converts ----------------
__global__ __launch_bounds__(384) void wbt_prep_kernel(const float* __restrict__ W,
                                                       short* __restrict__ WbT) {
    int j = blockIdx.x;       // 0..127
    int kk = threadIdx.x;     // 0..383
    WbT[j * K3 + kk] = f2bf(W[kk * DIM + j]);
}

__global__ __launch_bounds__(256) void convert_x_kernel(const float* __restrict__ x,
                                                        short* __restrict__ Xcat, int n32) {
    int tid = blockIdx.x * 256 + threadIdx.x;
    if (tid >= n32) return;
    int i = tid >> 5, seg = tid & 31;
    float4 v = *(const float4*)&x[(size_t)i * DIM + seg * 4];
    short4 o;
    o.x = f2bf(v.x); o.y = f2bf(v.y); o.z = f2bf(v.z); o.w = f2bf(v.w);
    *(short4*)&Xcat[(size_t)i * K3 + seg * 4] = o;
}

// ---------------- gather propagation (bf16 in, bf16 out), 4-edge unrolled ----
__global__ __launch_bounds__(256) void gather1_kernel(short* __restrict__ Xcat,
                                                      const int* __restrict__ row_ptr,
                                                      const int* __restrict__ colS,
                                                      const float* __restrict__ dinv, int n) {
    int wid = (blockIdx.x * 256 + threadIdx.x) >> 6;
    int lane = threadIdx.x & 63;
    if (wid >= n) return;
    int e = row_ptr[wid], end = row_ptr[wid + 1];
    const int base = lane * 2;
    float a0 = 0.f, a1 = 0.f, b0 = 0.f, b1 = 0.f;
    float c0 = 0.f, c1 = 0.f, d0 = 0.f, d1 = 0.f;
    for (; e + 3 < end; e += 4) {
        int i0 = colS[e], i1 = colS[e + 1], i2 = colS[e + 2], i3 = colS[e + 3];
        float w0 = dinv[i0], w1 = dinv[i1], w2 = dinv[i2], w3 = dinv[i3];
        unsigned p0 = *(const unsigned*)&Xcat[(size_t)i0 * K3 + base];
        unsigned p1 = *(const unsigned*)&Xcat[(size_t)i1 * K3 + base];
        unsigned p2 = *(const unsigned*)&Xcat[(size_t)i2 * K3 + base];
        unsigned p3 = *(const unsigned*)&Xcat[(size_t)i3 * K3 + base];
        a0 = fmaf(w0, bflo(p0), a0); a1 = fmaf(w0, bfhi(p0), a1);
        b0 = fmaf(w1, bflo(p1), b0); b1 = fmaf(w1, bfhi(p1), b1);
        c0 = fmaf(w2, bflo(p2), c0); c1 = fmaf(w2, bfhi(p2), c1);
        d0 = fmaf(w3, bflo(p3), d0); d1 = fmaf(w3, bfhi(p3), d1);
    }
    for (; e < end; ++e) {
        int i0 = colS[e];
        float w0 = dinv[i0];
        unsigned p0 = *(const unsigned*)&Xcat[(size_t)i0 * K3 + base];
        a0 = fmaf(w0, bflo(p0), a0); a1 = fmaf(w0, bfhi(p0), a1);
    }
    float s = -dinv[wid];
    float o0 = s * ((a0 + b0) + (c0 + d0));
    float o1 = s * ((a1 + b1) + (c1 + d1));
    unsigned pk = ((unsigned)(unsigned short)f2bf(o1) << 16) | (unsigned short)f2bf(o0);
    *(unsigned*)&Xcat[(size_t)wid * K3 + 128 + base] = pk;
}

__global__ __launch_bounds__(256) void gather2_kernel(short* __restrict__ Xcat,
                                                      const int* __restrict__ row_ptr,
                                                      const int* __restrict__ colS,
                                                      const float* __restrict__ dinv, int n) {
    int wid = (blockIdx.x * 256 + threadIdx.x) >> 6;
    int lane = threadIdx.x & 63;
    if (wid >= n) return;
    int e = row_ptr[wid], end = row_ptr[wid + 1];
    const int base = lane * 2;
    float a0 = 0.f, a1 = 0.f, b0 = 0.f, b1 = 0.f;
    float c0 = 0.f, c1 = 0.f, d0 = 0.f, d1 = 0.f;
    for (; e + 3 < end; e += 4) {
        int i0 = colS[e], i1 = colS[e + 1], i2 = colS[e + 2], i3 = colS[e + 3];
        float w0 = dinv[i0], w1 = dinv[i1], w2 = dinv[i2], w3 = dinv[i3];
        unsigned p0 = *(const unsigned*)&Xcat[(size_t)i0 * K3 + 128 + base];
        unsigned p1 = *(const unsigned*)&Xcat[(size_t)i1 * K3 + 128 + base];
        unsigned p2 = *(const unsigned*)&Xcat[(size_t)i2 * K3 + 128 + base];
        unsigned p3 = *(const unsigned*)&Xcat[(size_t)i3 * K3 + 128 + base];
        a0 = fmaf(w0, bflo(p0), a0); a1 = fmaf(w0, bfhi(p0), a1);
        b0 = fmaf(w1, bflo(p1), b0); b1 = fmaf(w1, bfhi(p1), b1);
        c0 = fmaf(w2, bflo(p2), c0); c1 = fmaf(w2, bfhi(p2), c1);
        d0 = fmaf(w3, bflo(p3), d0); d1 = fmaf(w3, bfhi(p3), d1);
    }
    for (; e < end; ++e) {
        int i0 = colS[e];
        float w0 = dinv[i0];
        unsigned p0 = *(const unsigned*)&Xcat[(size_t)i0 * K3 + 128 + base];
        a0 = fmaf(w0, bflo(p0), a0); a1 = fmaf(w0, bfhi(p0), a1);
    }
    float s = -2.f * dinv[wid];
    unsigned px = *(const unsigned*)&Xcat[(size_t)wid * K3 + base];  // bf16 x row
    float o0 = fmaf(s, (a0 + b0) + (c0 + d0), -bflo(px));
    float o1 = fmaf(s, (a1 + b1) + (c1 + d1), -bfhi(px));
    unsigned pk = ((unsigned)(unsigned short)f2bf(o1) << 16) | (unsigned short)f2bf(o0);
    *(unsigned*)&Xcat[(size_t)wid * K3 + 256 + base] = pk;
}

// ---------------- MFMA GEMM + bias + PReLU + fused channel stats ----------------
__global__ __launch_bounds__(256) void gemm_mfma_kernel(const short* __restrict__ Xcat,
                                                        const short* __restrict__ WbT,
                                                        const float* __restrict__ bias,
                                                        const float* __restrict__ prelu_a,
                                                        float* __restrict__ out,
                                                        float* __restrict__ stats, int n) {
    __shared__ short wlds[64 * 392];
    __shared__ float sredS[4][64], sredQ[4][64];

    const int tid = threadIdx.x;
    const int jb = blockIdx.y;
    const int wid = tid >> 6, lane = tid & 63;
    const int g = lane >> 4, l15 = lane & 15;
    const int rbase = blockIdx.x * 256 + wid * 64;

    #pragma unroll
    for (int c = 0; c < 12; ++c) {
        int chunk = tid + c * 256;           // 0..3071
        int row = chunk / 48, part = chunk % 48;
        *(short8*)&wlds[row * 392 + part * 8] =
            *(const short8*)&WbT[(size_t)(jb * 64 + row) * K3 + part * 8];
    }
    __syncthreads();

    const short* ap[4];
    #pragma unroll
    for (int ri = 0; ri < 4; ++ri) {
        int r = rbase + ri * 16 + l15;
        if (r >= n) r = n - 1;
        ap[ri] = Xcat + (size_t)r * K3 + g * 8;
    }

    f32x4 acc[4][4];
    #pragma unroll
    for (int ri = 0; ri < 4; ++ri)
        #pragma unroll
        for (int ci = 0; ci < 4; ++ci)
            acc[ri][ci] = (f32x4){0.f, 0.f, 0.f, 0.f};

    #pragma unroll
    for (int ks = 0; ks < 12; ++ks) {
        short8 a[4], b[4];
        #pragma unroll
        for (int ri = 0; ri < 4; ++ri)
            a[ri] = *(const short8*)(ap[ri] + ks * 32);
        #pragma unroll
        for (int ci = 0; ci < 4; ++ci)
            b[ci] = *(const short8*)&wlds[(ci * 16 + l15) * 392 + ks * 32 + g * 8];
        #pragma unroll
        for (int ri = 0; ri < 4; ++ri)
            #pragma unroll
            for (int ci = 0; ci < 4; ++ci)
                acc[ri][ci] = __builtin_amdgcn_mfma_f32_16x16x32_bf16(a[ri], b[ci],
                                                                      acc[ri][ci], 0, 0, 0);
    }

    const float ap_s = prelu_a[0];
    float bs[4];
    #pragma unroll
    for (int ci = 0; ci < 4; ++ci) bs[ci] = bias[jb * 64 + ci * 16 + l15];

    float sS[4] = {0.f, 0.f, 0.f, 0.f}, sQ[4] = {0.f, 0.f, 0.f, 0.f};
    #pragma unroll
    for (int ri = 0; ri < 4; ++ri) {
        #pragma unroll
        for (int ci = 0; ci < 4; ++ci) {
            int j = jb * 64 + ci * 16 + l15;
            #pragma unroll
            for (int reg = 0; reg < 4; ++reg) {
                int r = rbase + ri * 16 + 4 * g + reg;
                float v = acc[ri][ci][reg] + bs[ci];
                v = v > 0.f ? v : ap_s * v;
                if (r < n) {
                    out[(size_t)r * DIM + j] = v;
                } else {
                    v = 0.f;
                }
                sS[ci] += v;
                sQ[ci] += v * v;
            }
        }
    }
    #pragma unroll
    for (int ci = 0; ci < 4; ++ci) {
        sS[ci] += __shfl_xor(sS[ci], 16);
        sS[ci] += __shfl_xor(sS[ci], 32);
        sQ[ci] += __shfl_xor(sQ[ci], 16);
        sQ[ci] += __shfl_xor(sQ[ci], 32);
    }
    if (lane < 16) {
        #pragma unroll
        for (int ci = 0; ci < 4; ++ci) {
            sredS[wid][ci * 16 + l15] = sS[ci];
            sredQ[wid][ci * 16 + l15] = sQ[ci];
        }
    }
    __syncthreads();
    if (tid < 64) {
        float S = sredS[0][tid] + sredS[1][tid] + sredS[2][tid] + sredS[3][tid];
        float Q = sredQ[0][tid] + sredQ[1][tid] + sredQ[2][tid] + sredQ[3][tid];
        atomicAdd(&stats[jb * 64 + tid], S);
        atomicAdd(&stats[128 + jb * 64 + tid], Q);
    }
}

// ---------------- batchnorm ----------------
__global__ void bn_prep_kernel(float* __restrict__ stats, const float* __restrict__ gamma,
                               const float* __restrict__ beta, float invN) {
    int c = threadIdx.x;  // 128
    float mean = stats[c] * invN;
    float var = stats[128 + c] * invN - mean * mean;
    float sc = gamma[c] * rsqrtf(var + 1e-5f);
    stats[256 + c] = sc;
    stats[384 + c] = beta[c] - mean * sc;
}

__global__ __launch_bounds__(256) void bn_apply_kernel(float* __restrict__ out,
                                                       const float* __restrict__ scale,
                                                       const float* __restrict__ shift,
                                                       int total4) {
    int i0 = blockIdx.x * 256 + threadIdx.x;
    int stride = gridDim.x * 256;
    int c4 = i0 & 31;
    float4 sc = *(const float4*)&scale[c4 * 4];
    float4 sh = *(const float4*)&shift[c4 * 4];
    for (int i = i0; i < total4; i += stride) {
        float4 v = ((float4*)out)[i];
        v.x = v.x * sc.x + sh.x;
        v.y = v.y * sc.y + sh.y;
        v.z = v.z * sc.z + sh.z;
        v.w = v.w * sc.w + sh.w;
        ((float4*)out)[i] = v;
    }
}

extern "C" void kernel_launch(void* const* d_in, const int* in_sizes, int n_in,
                              void* d_out, int out_size, void* d_ws, size_t ws_size,
                              hipStream_t stream) {
    const float* x = (const float*)d_in[0];
    const int* ei = (const int*)d_in[1];
    const float* W = (const float*)d_in[2];
    const float* bias = (const float*)d_in[3];
    const float* prelu_a = (const float*)d_in[4];
    const float* gamma = (const float*)d_in[5];
    const float* beta = (const float*)d_in[6];
    float* out = (float*)d_out;

    const int N = in_sizes[0] / DIM;  // 100000
    const int E = in_sizes[1] / 2;    // 1600000
    const int* row = ei;
    const int* col = ei + E;

    const int NBLK = (E + CHUNK - 1) / CHUNK;   // 500
    const int NBUCK = (N + 255) >> 8;           // 391
    const int nflat = NBUCK * NBLK;             // 195500

    char* ws = (char*)d_ws;
    size_t off = 0;
    auto take = [&](size_t bytes) {
        size_t p = off;
        off = (off + bytes + 1023) & ~(size_t)1023;
        return p;
    };
    float* dinv      = (float*)(ws + take((size_t)N * 4));
    int* row_ptr     = (int*)(ws + take((size_t)(N + 1) * 4));
    int* blockSums   = (int*)(ws + take(256 * 4));
    float* stats     = (float*)(ws + take(512 * 4));     // sum | sumsq | scale | shift
    int* colS        = (int*)(ws + take((size_t)E * 4));
    int* M           = (int*)(ws + take((size_t)nflat * 4));
    int* Ms          = (int*)(ws + take((size_t)(nflat + 1) * 4));
    int* localPtr    = (int*)(ws + take((size_t)NBLK * NBUCK * 4));
    int* pairsLocal  = (int*)(ws + take((size_t)NBLK * CHUNK * 4));
    short* WbT       = (short*)(ws + take((size_t)DIM * K3 * 2));
    short* Xcat      = (short*)(ws + take((size_t)N * K3 * 2));

    (void)hipMemsetAsync(stats, 0, 512 * 4, stream);

    // CSR build (no global atomics)
    bin_kernel<<<NBLK, 256, 0, stream>>>(row, col, M, localPtr, pairsLocal, E, NBLK, NBUCK);
    int nb = (nflat + SCAN_ELEMS - 1) / SCAN_ELEMS;  // 191
    scan1_kernel<<<nb, SCAN_T, 0, stream>>>(M, Ms, blockSums, nflat);
    scan2_kernel<<<1, 256, 0, stream>>>(blockSums, nb);
    scan3_kernel<<<(nflat + 255) / 256, 256, 0, stream>>>(Ms, blockSums, nflat, E);
    csr_kernel<<<NBUCK, 256, 0, stream>>>(Ms, localPtr, pairsLocal, row_ptr, dinv, colS,
                                          E, N, NBLK, NBUCK);

    wbt_prep_kernel<<<DIM, 384, 0, stream>>>(W, WbT);
    convert_x_kernel<<<(N * 32 + 255) / 256, 256, 0, stream>>>(x, Xcat, N * 32);

    int gatherBlocks = (N * 64 + 255) / 256;
    gather1_kernel<<<gatherBlocks, 256, 0, stream>>>(Xcat, row_ptr, colS, dinv, N);
    gather2_kernel<<<gatherBlocks, 256, 0, stream>>>(Xcat, row_ptr, colS, dinv, N);

    dim3 ggrid((N + 255) / 256, 2);
    gemm_mfma_kernel<<<ggrid, 256, 0, stream>>>(Xcat, WbT, bias, prelu_a, out, stats, N);

    bn_prep_kernel<<<1, 128, 0, stream>>>(stats, gamma, beta, 1.0f / (float)N);
    bn_apply_kernel<<<2048, 256, 0, stream>>>(out, stats + 256, stats + 384, N * 32);
}